// Round 3
// baseline (1815.132 us; speedup 1.0000x reference)
//
#include <hip/hip_runtime.h>
#include <hip/hip_bf16.h>

#define D 128

// ---- dtype detection: are float inputs f32 or bf16 on device? ----
// Reads first 4096 u16 words of node_emb. bf16-truth: exponents cluster near
// 0x7F (N(0,1)), ~0 extreme. f32-truth: low halves are mantissa garbage with
// uniform exponents, ~43% extreme. flag=1 => f32.
__global__ __launch_bounds__(256) void detect_kernel(const unsigned short* __restrict__ x,
                                                     int* __restrict__ flag) {
    int t = threadIdx.x;
    int cnt = 0;
    for (int i = t; i < 4096; i += 256) {
        unsigned e = (x[i] >> 7) & 0xFFu;
        if (e == 0xFFu || e >= 0x90u || (e >= 1u && e <= 0x6Eu)) cnt++;
    }
    __shared__ int sh[256];
    sh[t] = cnt;
    __syncthreads();
    for (int off = 128; off; off >>= 1) {
        if (t < off) sh[t] += sh[t + off];
        __syncthreads();
    }
    if (t == 0) flag[0] = (sh[0] > 800) ? 1 : 0;
}

struct ConvBatch {
    const void* src[14];
    __hip_bfloat16* dst[14];
    int n[14];
};

__global__ __launch_bounds__(256) void conv_weights_kernel(ConvBatch cb,
                                                           const int* __restrict__ flag) {
    int a = blockIdx.x;
    const void* s = cb.src[a];
    __hip_bfloat16* d = cb.dst[a];
    int n = cb.n[a];
    int f = flag[0];
    for (int i = threadIdx.x; i < n; i += 256) {
        d[i] = f ? __float2bfloat16(((const float*)s)[i])
                 : ((const __hip_bfloat16*)s)[i];
    }
}

__global__ __launch_bounds__(256) void conv_x_kernel(const void* __restrict__ src,
                                                     __hip_bfloat16* __restrict__ dst,
                                                     int n, const int* __restrict__ flag) {
    int i = blockIdx.x * 256 + threadIdx.x;
    int f = flag[0];
    if (i < n)
        dst[i] = f ? __float2bfloat16(((const float*)src)[i])
                   : ((const __hip_bfloat16*)src)[i];
}

__global__ __launch_bounds__(256) void zero_kernel(int* p, int n) {
    int i = blockIdx.x * 256 + threadIdx.x;
    if (i < n) p[i] = 0;
}

__global__ __launch_bounds__(256) void count_kernel(const int* __restrict__ keys, int E,
                                                    int* __restrict__ deg) {
    int i = blockIdx.x * 256 + threadIdx.x;
    if (i < E) atomicAdd(&deg[keys[i]], 1);
}

// gridDim.x = 4 arrays; each block scans its array of length N.
// degcur: degrees in, exclusive-prefix (scatter cursor) out.
__global__ __launch_bounds__(256) void scan_kernel(int* __restrict__ degcur,
                                                   int* __restrict__ indptr, int N) {
    int a = blockIdx.x;
    int* d = degcur + (size_t)a * N;
    int* ip = indptr + (size_t)a * (N + 1);
    int t = threadIdx.x;
    int C = (N + 255) / 256;
    int lo = t * C;
    int hi = lo + C; if (hi > N) hi = N; if (lo > N) lo = N;
    int s = 0;
    for (int i = lo; i < hi; i++) s += d[i];
    __shared__ int tmp[256];
    tmp[t] = s;
    __syncthreads();
    for (int off = 1; off < 256; off <<= 1) {
        int v = (t >= off) ? tmp[t - off] : 0;
        __syncthreads();
        tmp[t] += v;
        __syncthreads();
    }
    int run = tmp[t] - s;
    for (int i = lo; i < hi; i++) {
        int dv = d[i];
        ip[i] = run;
        d[i] = run;
        run += dv;
    }
    if (t == 255) ip[N] = run;
}

__global__ __launch_bounds__(256) void scatter_kernel(const int* __restrict__ keys, int E,
                                                      int* __restrict__ cursor,
                                                      int* __restrict__ ids) {
    int i = blockIdx.x * 256 + threadIdx.x;
    if (i < E) {
        int p = atomicAdd(&cursor[keys[i]], 1);
        ids[p] = i;
    }
}

// part0[n] = x_n @ W[0:128,:]   ; part1[n] = x_n @ W[128:256,:] + bias
__global__ __launch_bounds__(256) void gemm2_kernel(const __hip_bfloat16* __restrict__ X,
                                                    const __hip_bfloat16* __restrict__ W,
                                                    const __hip_bfloat16* __restrict__ bias,
                                                    __hip_bfloat16* __restrict__ part0,
                                                    __hip_bfloat16* __restrict__ part1, int N) {
    __shared__ float xs[32][D];
    int n0 = blockIdx.x * 32;
    for (int idx = threadIdx.x; idx < 32 * D; idx += 256) {
        int r = idx >> 7, c = idx & 127;
        int n = n0 + r;
        xs[r][c] = (n < N) ? __bfloat162float(X[(size_t)n * D + c]) : 0.f;
    }
    __syncthreads();
    int jj = threadIdx.x & 127;
    int half = threadIdx.x >> 7;
    const __hip_bfloat16* Wp = W + (size_t)half * D * D;
    float acc[32];
#pragma unroll
    for (int i = 0; i < 32; i++) acc[i] = 0.f;
    for (int k = 0; k < D; k++) {
        float w = __bfloat162float(Wp[(size_t)k * D + jj]);
#pragma unroll
        for (int i = 0; i < 32; i++) acc[i] += xs[i][k] * w;
    }
    float b = half ? __bfloat162float(bias[jj]) : 0.f;
    __hip_bfloat16* outp = half ? part1 : part0;
    for (int i = 0; i < 32; i++) {
        int n = n0 + i;
        if (n < N) outp[(size_t)n * D + jj] = __float2bfloat16(acc[i] + b);
    }
}

// score[e] = sum_j tanh(Pkey[key[e]][j] + Poth[oth[e]][j]) * w[j] + wb
__global__ __launch_bounds__(256) void edge_score_kernel(const __hip_bfloat16* __restrict__ Pkey,
                                                         const __hip_bfloat16* __restrict__ Poth,
                                                         const int* __restrict__ keys,
                                                         const int* __restrict__ oths,
                                                         const __hip_bfloat16* __restrict__ w,
                                                         const __hip_bfloat16* __restrict__ wb,
                                                         float* __restrict__ eij, int E) {
    int wid = (int)((blockIdx.x * 256 + threadIdx.x) >> 6);
    int lane = threadIdx.x & 63;
    if (wid >= E) return;
    int key = keys[wid], oth = oths[wid];
    const __hip_bfloat162* a = (const __hip_bfloat162*)(Pkey + (size_t)key * D);
    const __hip_bfloat162* b = (const __hip_bfloat162*)(Poth + (size_t)oth * D);
    __hip_bfloat162 av = a[lane], bv = b[lane];
    __hip_bfloat162 wv = ((const __hip_bfloat162*)w)[lane];
    float p = tanhf(__bfloat162float(av.x) + __bfloat162float(bv.x)) * __bfloat162float(wv.x)
            + tanhf(__bfloat162float(av.y) + __bfloat162float(bv.y)) * __bfloat162float(wv.y);
    for (int off = 32; off; off >>= 1) p += __shfl_xor(p, off);
    if (lane == 0) eij[wid] = p + __bfloat162float(wb[0]);
}

// One wave per node: fused segment softmax + weighted aggregation, both sides.
__global__ __launch_bounds__(256) void attn_node_kernel(
    const __hip_bfloat16* __restrict__ X,
    const float* __restrict__ eij_e, const int* __restrict__ ip_e,
    const int* __restrict__ ids_e, const int* __restrict__ oth_e,
    const float* __restrict__ eij_r, const int* __restrict__ ip_r,
    const int* __restrict__ ids_r, const int* __restrict__ oth_r,
    __hip_bfloat16* __restrict__ attn_agg, int N) {
    int wid = (int)((blockIdx.x * 256 + threadIdx.x) >> 6);
    int lane = threadIdx.x & 63;
    if (wid >= N) return;
    float accx = 0.f, accy = 0.f;
    for (int side = 0; side < 2; side++) {
        const float* eij = side ? eij_r : eij_e;
        const int* ip  = side ? ip_r  : ip_e;
        const int* ids = side ? ids_r : ids_e;
        const int* oth = side ? oth_r : oth_e;
        int s0 = ip[wid], s1 = ip[wid + 1];
        if (s1 == s0) continue;
        float m = 0.f;  // torch amax include_self over zeros => floor at 0
        for (int i = s0 + lane; i < s1; i += 64) m = fmaxf(m, eij[ids[i]]);
        for (int off = 32; off; off >>= 1) m = fmaxf(m, __shfl_xor(m, off));
        float ssum = 0.f;
        for (int i = s0 + lane; i < s1; i += 64) ssum += __expf(eij[ids[i]] - m);
        for (int off = 32; off; off >>= 1) ssum += __shfl_xor(ssum, off);
        float inv = 1.f / (ssum + 1e-9f);
        for (int i = s0; i < s1; i++) {
            int id = ids[i];
            float p = __expf(eij[id] - m) * inv;
            const __hip_bfloat162* xr = (const __hip_bfloat162*)(X + (size_t)oth[id] * D);
            __hip_bfloat162 xv = xr[lane];
            accx += p * __bfloat162float(xv.x);
            accy += p * __bfloat162float(xv.y);
        }
    }
    __hip_bfloat162 ov;
    ov.x = __float2bfloat16(accx);
    ov.y = __float2bfloat16(accy);
    ((__hip_bfloat162*)(attn_agg + (size_t)wid * D))[lane] = ov;
}

// One wave per node: mean over ee- and rr-neighbours.
__global__ __launch_bounds__(256) void mean_node_kernel(
    const __hip_bfloat16* __restrict__ X,
    const int* __restrict__ ip_ee, const int* __restrict__ ids_ee, const int* __restrict__ dst_ee,
    const int* __restrict__ ip_rr, const int* __restrict__ ids_rr, const int* __restrict__ dst_rr,
    __hip_bfloat16* __restrict__ mean_agg, int N) {
    int wid = (int)((blockIdx.x * 256 + threadIdx.x) >> 6);
    int lane = threadIdx.x & 63;
    if (wid >= N) return;
    float accx = 0.f, accy = 0.f;
    int cnt = 0;
    for (int side = 0; side < 2; side++) {
        const int* ip  = side ? ip_rr  : ip_ee;
        const int* ids = side ? ids_rr : ids_ee;
        const int* dst = side ? dst_rr : dst_ee;
        int s0 = ip[wid], s1 = ip[wid + 1];
        cnt += s1 - s0;
        for (int i = s0; i < s1; i++) {
            int id = ids[i];
            const __hip_bfloat162* xr = (const __hip_bfloat162*)(X + (size_t)dst[id] * D);
            __hip_bfloat162 xv = xr[lane];
            accx += __bfloat162float(xv.x);
            accy += __bfloat162float(xv.y);
        }
    }
    float inv = 1.f / fmaxf((float)cnt, 1.f);
    __hip_bfloat162 ov;
    ov.x = __float2bfloat16(accx * inv);
    ov.y = __float2bfloat16(accy * inv);
    ((__hip_bfloat162*)(mean_agg + (size_t)wid * D))[lane] = ov;
}

// out = tanh(X@W1+b1) + tanh(A@W2+b2) + tanh(M@W3+b3); dual-dtype store.
__global__ __launch_bounds__(128) void final_kernel(
    const __hip_bfloat16* __restrict__ X, const __hip_bfloat16* __restrict__ Agg,
    const __hip_bfloat16* __restrict__ Mn,
    const __hip_bfloat16* __restrict__ W1, const __hip_bfloat16* __restrict__ b1,
    const __hip_bfloat16* __restrict__ W2, const __hip_bfloat16* __restrict__ b2,
    const __hip_bfloat16* __restrict__ W3, const __hip_bfloat16* __restrict__ b3,
    void* __restrict__ out, const int* __restrict__ flag, int N) {
    __shared__ float s[3][16][D];
    int n0 = blockIdx.x * 16;
    for (int idx = threadIdx.x; idx < 16 * D; idx += 128) {
        int r = idx >> 7, c = idx & 127;
        int n = n0 + r;
        if (n < N) {
            s[0][r][c] = __bfloat162float(X[(size_t)n * D + c]);
            s[1][r][c] = __bfloat162float(Agg[(size_t)n * D + c]);
            s[2][r][c] = __bfloat162float(Mn[(size_t)n * D + c]);
        } else {
            s[0][r][c] = 0.f; s[1][r][c] = 0.f; s[2][r][c] = 0.f;
        }
    }
    __syncthreads();
    int jj = threadIdx.x;
    float oacc[16];
#pragma unroll
    for (int i = 0; i < 16; i++) oacc[i] = 0.f;
    const __hip_bfloat16* Ws[3] = {W1, W2, W3};
    const __hip_bfloat16* bs[3] = {b1, b2, b3};
    for (int m = 0; m < 3; m++) {
        float acc[16];
#pragma unroll
        for (int i = 0; i < 16; i++) acc[i] = 0.f;
        const __hip_bfloat16* W = Ws[m];
        for (int k = 0; k < D; k++) {
            float w = __bfloat162float(W[(size_t)k * D + jj]);
#pragma unroll
            for (int i = 0; i < 16; i++) acc[i] += s[m][i][k] * w;
        }
        float bb = __bfloat162float(bs[m][jj]);
#pragma unroll
        for (int i = 0; i < 16; i++) oacc[i] += tanhf(acc[i] + bb);
    }
    int f = flag[0];
    for (int i = 0; i < 16; i++) {
        int n = n0 + i;
        if (n < N) {
            if (f) ((float*)out)[(size_t)n * D + jj] = oacc[i];
            else   ((__hip_bfloat16*)out)[(size_t)n * D + jj] = __float2bfloat16(oacc[i]);
        }
    }
}

extern "C" void kernel_launch(void* const* d_in, const int* in_sizes, int n_in,
                              void* d_out, int out_size, void* d_ws, size_t ws_size,
                              hipStream_t stream) {
    const int* er_src = (const int*)d_in[15];
    const int* er_dst = (const int*)d_in[16];
    const int* ee_src = (const int*)d_in[17];
    const int* ee_dst = (const int*)d_in[18];
    const int* rr_src = (const int*)d_in[19];
    const int* rr_dst = (const int*)d_in[20];

    int N   = in_sizes[0] / D;
    int Eer = in_sizes[15];
    int Eee = in_sizes[17];
    int Err = in_sizes[19];

    char* ws = (char*)d_ws;
    size_t off = 0;
    auto alloc = [&](size_t bytes) -> void* {
        void* p = ws + off;
        off = (off + bytes + 255) & ~(size_t)255;
        return p;
    };
    int* flag   = (int*)alloc(256);
    int* ids_es = (int*)alloc((size_t)Eer * 4);
    int* ids_rd = (int*)alloc((size_t)Eer * 4);
    int* ids_ee = (int*)alloc((size_t)Eee * 4);
    int* ids_rr = (int*)alloc((size_t)Err * 4);
    int* indptr = (int*)alloc((size_t)4 * (N + 1) * 4);
    int* degcur = (int*)alloc((size_t)4 * N * 4);
    float* eij_e = (float*)alloc((size_t)Eer * 4);
    float* eij_r = (float*)alloc((size_t)Eer * 4);
    __hip_bfloat16* Xc = (__hip_bfloat16*)alloc((size_t)N * D * 2);
    __hip_bfloat16* part0 = (__hip_bfloat16*)alloc((size_t)N * D * 2);
    __hip_bfloat16* part1 = (__hip_bfloat16*)alloc((size_t)N * D * 2);
    __hip_bfloat16* attn_agg = part0;  // parts die after 2nd edge_score
    __hip_bfloat16* mean_agg = part1;
    // canonical bf16 weight copies (14 tensors)
    ConvBatch cb;
    int widx[14] = {1, 2, 3, 4, 5, 6, 7, 8, 9, 10, 11, 12, 13, 14};
    for (int i = 0; i < 14; i++) {
        cb.src[i] = d_in[widx[i]];
        cb.n[i] = in_sizes[widx[i]];
        cb.dst[i] = (__hip_bfloat16*)alloc((size_t)cb.n[i] * 2);
    }
    const __hip_bfloat16* Wae = cb.dst[0];
    const __hip_bfloat16* bae = cb.dst[1];
    const __hip_bfloat16* w0w = cb.dst[2];
    const __hip_bfloat16* w0b = cb.dst[3];
    const __hip_bfloat16* War = cb.dst[4];
    const __hip_bfloat16* bar_= cb.dst[5];
    const __hip_bfloat16* w1w = cb.dst[6];
    const __hip_bfloat16* w1b = cb.dst[7];
    const __hip_bfloat16* W1  = cb.dst[8];
    const __hip_bfloat16* b1  = cb.dst[9];
    const __hip_bfloat16* W2  = cb.dst[10];
    const __hip_bfloat16* b2  = cb.dst[11];
    const __hip_bfloat16* W3  = cb.dst[12];
    const __hip_bfloat16* b3  = cb.dst[13];
    (void)n_in; (void)out_size;
    if (off > ws_size) return;  // diagnostic: zeros out => absmax ~2.58, not NaN

    // ---- dtype detect + canonicalize to bf16 ----
    detect_kernel<<<1, 256, 0, stream>>>((const unsigned short*)d_in[0], flag);
    conv_weights_kernel<<<14, 256, 0, stream>>>(cb, flag);
    conv_x_kernel<<<(N * D + 255) / 256, 256, 0, stream>>>(d_in[0], Xc, N * D, flag);

    // ---- CSR build (4 keys: er_src, er_dst, ee_src, rr_src) ----
    zero_kernel<<<(4 * N + 255) / 256, 256, 0, stream>>>(degcur, 4 * N);
    count_kernel<<<(Eer + 255) / 256, 256, 0, stream>>>(er_src, Eer, degcur);
    count_kernel<<<(Eer + 255) / 256, 256, 0, stream>>>(er_dst, Eer, degcur + N);
    count_kernel<<<(Eee + 255) / 256, 256, 0, stream>>>(ee_src, Eee, degcur + 2 * N);
    count_kernel<<<(Err + 255) / 256, 256, 0, stream>>>(rr_src, Err, degcur + 3 * N);
    scan_kernel<<<4, 256, 0, stream>>>(degcur, indptr, N);
    scatter_kernel<<<(Eer + 255) / 256, 256, 0, stream>>>(er_src, Eer, degcur, ids_es);
    scatter_kernel<<<(Eer + 255) / 256, 256, 0, stream>>>(er_dst, Eer, degcur + N, ids_rd);
    scatter_kernel<<<(Eee + 255) / 256, 256, 0, stream>>>(ee_src, Eee, degcur + 2 * N, ids_ee);
    scatter_kernel<<<(Err + 255) / 256, 256, 0, stream>>>(rr_src, Err, degcur + 3 * N, ids_rr);

    int GB = (N + 31) / 32;
    int EW = (Eer + 3) / 4;  // one wave per edge

    // entity side: pair=[r,h]@Wae; key=src(h part,+bae), oth=dst(r part)
    gemm2_kernel<<<GB, 256, 0, stream>>>(Xc, Wae, bae, part0, part1, N);
    edge_score_kernel<<<EW, 256, 0, stream>>>(part1, part0, er_src, er_dst, w0w, w0b, eij_e, Eer);

    // relation side: pair=[h,r]@War; key=dst(r part,+bar), oth=src(h part)
    gemm2_kernel<<<GB, 256, 0, stream>>>(Xc, War, bar_, part0, part1, N);
    edge_score_kernel<<<EW, 256, 0, stream>>>(part1, part0, er_dst, er_src, w1w, w1b, eij_r, Eer);

    int NW = (N + 3) / 4;  // one wave per node
    attn_node_kernel<<<NW, 256, 0, stream>>>(Xc, eij_e, indptr, ids_es, er_dst,
                                             eij_r, indptr + (N + 1), ids_rd, er_src,
                                             attn_agg, N);
    mean_node_kernel<<<NW, 256, 0, stream>>>(Xc, indptr + 2 * (N + 1), ids_ee, ee_dst,
                                             indptr + 3 * (N + 1), ids_rr, rr_dst,
                                             mean_agg, N);
    final_kernel<<<(N + 15) / 16, 128, 0, stream>>>(Xc, attn_agg, mean_agg,
                                                    W1, b1, W2, b2, W3, b3,
                                                    d_out, flag, N);
}

// Round 4
// 1350.183 us; speedup vs baseline: 1.3444x; 1.3444x over previous
//
#include <hip/hip_runtime.h>
#include <hip/hip_bf16.h>

#define D 128

typedef __bf16 bf16x8 __attribute__((ext_vector_type(8)));
typedef float f32x4 __attribute__((ext_vector_type(4)));

// ---- dtype detection: are float inputs f32 or bf16 on device? flag=1 => f32.
__global__ __launch_bounds__(256) void detect_kernel(const unsigned short* __restrict__ x,
                                                     int* __restrict__ flag) {
    int t = threadIdx.x;
    int cnt = 0;
    for (int i = t; i < 4096; i += 256) {
        unsigned e = (x[i] >> 7) & 0xFFu;
        if (e == 0xFFu || e >= 0x90u || (e >= 1u && e <= 0x6Eu)) cnt++;
    }
    __shared__ int sh[256];
    sh[t] = cnt;
    __syncthreads();
    for (int off = 128; off; off >>= 1) {
        if (t < off) sh[t] += sh[t + off];
        __syncthreads();
    }
    if (t == 0) flag[0] = (sh[0] > 800) ? 1 : 0;
}

struct ConvBatch {
    const void* src[14];
    __hip_bfloat16* dst[14];
    int n[14];
};

__global__ __launch_bounds__(256) void conv_weights_kernel(ConvBatch cb,
                                                           const int* __restrict__ flag) {
    int a = blockIdx.x;
    const void* s = cb.src[a];
    __hip_bfloat16* d = cb.dst[a];
    int n = cb.n[a];
    int f = flag[0];
    for (int i = threadIdx.x; i < n; i += 256) {
        d[i] = f ? __float2bfloat16(((const float*)s)[i])
                 : ((const __hip_bfloat16*)s)[i];
    }
}

__global__ __launch_bounds__(256) void conv_x_kernel(const void* __restrict__ src,
                                                     __hip_bfloat16* __restrict__ dst,
                                                     int n, const int* __restrict__ flag) {
    int i = blockIdx.x * 256 + threadIdx.x;
    int f = flag[0];
    if (i < n)
        dst[i] = f ? __float2bfloat16(((const float*)src)[i])
                   : ((const __hip_bfloat16*)src)[i];
}

// ---- weight transpose: 7 independent 128x128 blocks -> Wt[c][k] = W[k][c] (bf16)
struct TransBatch {
    const void* base[7];
    int off[7];                 // element offset into base
    unsigned short* dst[7];
};

__global__ __launch_bounds__(256) void trans_kernel(TransBatch tb,
                                                    const int* __restrict__ flag) {
    int a = blockIdx.x;
    int f = flag[0];
    const float* sf = (const float*)tb.base[a] + tb.off[a];
    const unsigned short* sb = (const unsigned short*)tb.base[a] + tb.off[a];
    unsigned short* d = tb.dst[a];
    for (int idx = threadIdx.x; idx < 128 * 128; idx += 256) {
        int k = idx >> 7, c = idx & 127;
        __hip_bfloat16 v;
        if (f) v = __float2bfloat16(sf[idx]);
        else   v = *(const __hip_bfloat16*)&sb[idx];
        d[c * 128 + k] = *(unsigned short*)&v;
    }
}

__global__ __launch_bounds__(256) void zero_kernel(int* p, int n) {
    int i = blockIdx.x * 256 + threadIdx.x;
    if (i < n) p[i] = 0;
}

__global__ __launch_bounds__(256) void count_kernel(const int* __restrict__ keys, int E,
                                                    int* __restrict__ deg) {
    int i = blockIdx.x * 256 + threadIdx.x;
    if (i < E) atomicAdd(&deg[keys[i]], 1);
}

// degcur: degrees in, exclusive-prefix (scatter cursor) out; 4 arrays.
__global__ __launch_bounds__(256) void scan_kernel(int* __restrict__ degcur,
                                                   int* __restrict__ indptr, int N) {
    int a = blockIdx.x;
    int* d = degcur + (size_t)a * N;
    int* ip = indptr + (size_t)a * (N + 1);
    int t = threadIdx.x;
    int C = (N + 255) / 256;
    int lo = t * C;
    int hi = lo + C; if (hi > N) hi = N; if (lo > N) lo = N;
    int s = 0;
    for (int i = lo; i < hi; i++) s += d[i];
    __shared__ int tmp[256];
    tmp[t] = s;
    __syncthreads();
    for (int off = 1; off < 256; off <<= 1) {
        int v = (t >= off) ? tmp[t - off] : 0;
        __syncthreads();
        tmp[t] += v;
        __syncthreads();
    }
    int run = tmp[t] - s;
    for (int i = lo; i < hi; i++) {
        int dv = d[i];
        ip[i] = run;
        d[i] = run;
        run += dv;
    }
    if (t == 255) ip[N] = run;
}

__global__ __launch_bounds__(256) void scatter_kernel(const int* __restrict__ keys, int E,
                                                      int* __restrict__ cursor,
                                                      int* __restrict__ ids) {
    int i = blockIdx.x * 256 + threadIdx.x;
    if (i < E) {
        int p = atomicAdd(&cursor[keys[i]], 1);
        ids[p] = i;
    }
}

// ---- MFMA GEMM: parts[n] = X[n] @ {Wt rows 0..127 | 128..255}^T (+bias on part1)
// Block: 64 rows, 4 waves; wave w computes rows w*16..w*16+15 x 256 cols.
// Wt[c][k] layout => B-frag is contiguous 16B. A staged in LDS (+8 pad).
__global__ __launch_bounds__(256) void gemm2_mfma_kernel(
    const __hip_bfloat16* __restrict__ X,
    const unsigned short* __restrict__ Wt,      // 256 x 128, Wt[c][k]
    const __hip_bfloat16* __restrict__ bias,    // 128 (part1 only)
    __hip_bfloat16* __restrict__ part0,
    __hip_bfloat16* __restrict__ part1, int N) {
    __shared__ __align__(16) unsigned short As[64 * 136];
    int n0 = blockIdx.x * 64;
    for (int idx = threadIdx.x; idx < 64 * 16; idx += 256) {
        int r = idx >> 4, ch = idx & 15;
        uint4 v = make_uint4(0u, 0u, 0u, 0u);
        int n = n0 + r;
        if (n < N) v = ((const uint4*)(X + (size_t)n * D))[ch];
        *(uint4*)&As[r * 136 + ch * 8] = v;
    }
    __syncthreads();
    int w = threadIdx.x >> 6, lane = threadIdx.x & 63;
    int n15 = lane & 15, quad = lane >> 4;
    const unsigned short* arow = &As[(w * 16 + n15) * 136 + quad * 8];
    bf16x8 af[4];
#pragma unroll
    for (int t = 0; t < 4; t++) af[t] = *(const bf16x8*)(arow + t * 32);
    for (int c = 0; c < 16; c++) {
        f32x4 acc = {0.f, 0.f, 0.f, 0.f};
        const unsigned short* bbase = Wt + (size_t)(c * 16 + n15) * D + quad * 8;
#pragma unroll
        for (int t = 0; t < 4; t++)
            acc = __builtin_amdgcn_mfma_f32_16x16x32_bf16(
                af[t], *(const bf16x8*)(bbase + t * 32), acc, 0, 0, 0);
        float b;
        __hip_bfloat16* outp;
        int col;
        if (c < 8) { outp = part0; col = c * 16 + n15; b = 0.f; }
        else       { outp = part1; col = c * 16 + n15 - 128;
                     b = __bfloat162float(bias[col]); }
#pragma unroll
        for (int i = 0; i < 4; i++) {
            int row = n0 + w * 16 + quad * 4 + i;
            if (row < N) outp[(size_t)row * D + col] = __float2bfloat16(acc[i] + b);
        }
    }
}

// ---- MFMA final: out = tanh(X@W1+b1)+tanh(A@W2+b2)+tanh(M@W3+b3)
__global__ __launch_bounds__(256) void final_mfma_kernel(
    const __hip_bfloat16* __restrict__ X, const __hip_bfloat16* __restrict__ Agg,
    const __hip_bfloat16* __restrict__ Mn,
    const unsigned short* __restrict__ Wt1, const __hip_bfloat16* __restrict__ b1,
    const unsigned short* __restrict__ Wt2, const __hip_bfloat16* __restrict__ b2,
    const unsigned short* __restrict__ Wt3, const __hip_bfloat16* __restrict__ b3,
    void* __restrict__ out, const int* __restrict__ flag, int N) {
    __shared__ __align__(16) unsigned short As[64 * 136];
    int n0 = blockIdx.x * 64;
    int w = threadIdx.x >> 6, lane = threadIdx.x & 63;
    int n15 = lane & 15, quad = lane >> 4;
    float osum[8][4];
#pragma unroll
    for (int c = 0; c < 8; c++)
#pragma unroll
        for (int i = 0; i < 4; i++) osum[c][i] = 0.f;
    const __hip_bfloat16* srcs[3] = {X, Agg, Mn};
    const unsigned short* Wts[3] = {Wt1, Wt2, Wt3};
    const __hip_bfloat16* bs[3] = {b1, b2, b3};
    for (int m = 0; m < 3; m++) {
        __syncthreads();   // As reuse: previous iter's reads done
        const __hip_bfloat16* S = srcs[m];
        for (int idx = threadIdx.x; idx < 64 * 16; idx += 256) {
            int r = idx >> 4, ch = idx & 15;
            uint4 v = make_uint4(0u, 0u, 0u, 0u);
            int n = n0 + r;
            if (n < N) v = ((const uint4*)(S + (size_t)n * D))[ch];
            *(uint4*)&As[r * 136 + ch * 8] = v;
        }
        __syncthreads();
        const unsigned short* arow = &As[(w * 16 + n15) * 136 + quad * 8];
        bf16x8 af[4];
#pragma unroll
        for (int t = 0; t < 4; t++) af[t] = *(const bf16x8*)(arow + t * 32);
        const unsigned short* Wm = Wts[m];
        for (int c = 0; c < 8; c++) {
            f32x4 acc = {0.f, 0.f, 0.f, 0.f};
            const unsigned short* bbase = Wm + (size_t)(c * 16 + n15) * D + quad * 8;
#pragma unroll
            for (int t = 0; t < 4; t++)
                acc = __builtin_amdgcn_mfma_f32_16x16x32_bf16(
                    af[t], *(const bf16x8*)(bbase + t * 32), acc, 0, 0, 0);
            float bb = __bfloat162float(bs[m][c * 16 + n15]);
#pragma unroll
            for (int i = 0; i < 4; i++) osum[c][i] += tanhf(acc[i] + bb);
        }
    }
    int f = flag[0];
    for (int c = 0; c < 8; c++) {
        int col = c * 16 + n15;
#pragma unroll
        for (int i = 0; i < 4; i++) {
            int row = n0 + w * 16 + quad * 4 + i;
            if (row < N) {
                if (f) ((float*)out)[(size_t)row * D + col] = osum[c][i];
                else   ((__hip_bfloat16*)out)[(size_t)row * D + col] =
                           __float2bfloat16(osum[c][i]);
            }
        }
    }
}

// score[e] = sum_j tanh(Pkey[key[e]][j] + Poth[oth[e]][j]) * w[j] + wb
__global__ __launch_bounds__(256) void edge_score_kernel(const __hip_bfloat16* __restrict__ Pkey,
                                                         const __hip_bfloat16* __restrict__ Poth,
                                                         const int* __restrict__ keys,
                                                         const int* __restrict__ oths,
                                                         const __hip_bfloat16* __restrict__ w,
                                                         const __hip_bfloat16* __restrict__ wb,
                                                         float* __restrict__ eij, int E) {
    int wid = (int)((blockIdx.x * 256 + threadIdx.x) >> 6);
    int lane = threadIdx.x & 63;
    if (wid >= E) return;
    int key = keys[wid], oth = oths[wid];
    const __hip_bfloat162* a = (const __hip_bfloat162*)(Pkey + (size_t)key * D);
    const __hip_bfloat162* b = (const __hip_bfloat162*)(Poth + (size_t)oth * D);
    __hip_bfloat162 av = a[lane], bv = b[lane];
    __hip_bfloat162 wv = ((const __hip_bfloat162*)w)[lane];
    float p = tanhf(__bfloat162float(av.x) + __bfloat162float(bv.x)) * __bfloat162float(wv.x)
            + tanhf(__bfloat162float(av.y) + __bfloat162float(bv.y)) * __bfloat162float(wv.y);
    for (int off = 32; off; off >>= 1) p += __shfl_xor(p, off);
    if (lane == 0) eij[wid] = p + __bfloat162float(wb[0]);
}

// One wave per node: fused segment softmax + weighted aggregation, both sides.
__global__ __launch_bounds__(256) void attn_node_kernel(
    const __hip_bfloat16* __restrict__ X,
    const float* __restrict__ eij_e, const int* __restrict__ ip_e,
    const int* __restrict__ ids_e, const int* __restrict__ oth_e,
    const float* __restrict__ eij_r, const int* __restrict__ ip_r,
    const int* __restrict__ ids_r, const int* __restrict__ oth_r,
    __hip_bfloat16* __restrict__ attn_agg, int N) {
    int wid = (int)((blockIdx.x * 256 + threadIdx.x) >> 6);
    int lane = threadIdx.x & 63;
    if (wid >= N) return;
    float accx = 0.f, accy = 0.f;
    for (int side = 0; side < 2; side++) {
        const float* eij = side ? eij_r : eij_e;
        const int* ip  = side ? ip_r  : ip_e;
        const int* ids = side ? ids_r : ids_e;
        const int* oth = side ? oth_r : oth_e;
        int s0 = ip[wid], s1 = ip[wid + 1];
        if (s1 == s0) continue;
        float m = 0.f;  // torch amax include_self over zeros => floor at 0
        for (int i = s0 + lane; i < s1; i += 64) m = fmaxf(m, eij[ids[i]]);
        for (int off = 32; off; off >>= 1) m = fmaxf(m, __shfl_xor(m, off));
        float ssum = 0.f;
        for (int i = s0 + lane; i < s1; i += 64) ssum += __expf(eij[ids[i]] - m);
        for (int off = 32; off; off >>= 1) ssum += __shfl_xor(ssum, off);
        float inv = 1.f / (ssum + 1e-9f);
        for (int i = s0; i < s1; i++) {
            int id = ids[i];
            float p = __expf(eij[id] - m) * inv;
            const __hip_bfloat162* xr = (const __hip_bfloat162*)(X + (size_t)oth[id] * D);
            __hip_bfloat162 xv = xr[lane];
            accx += p * __bfloat162float(xv.x);
            accy += p * __bfloat162float(xv.y);
        }
    }
    __hip_bfloat162 ov;
    ov.x = __float2bfloat16(accx);
    ov.y = __float2bfloat16(accy);
    ((__hip_bfloat162*)(attn_agg + (size_t)wid * D))[lane] = ov;
}

// One wave per node: mean over ee- and rr-neighbours.
__global__ __launch_bounds__(256) void mean_node_kernel(
    const __hip_bfloat16* __restrict__ X,
    const int* __restrict__ ip_ee, const int* __restrict__ ids_ee, const int* __restrict__ dst_ee,
    const int* __restrict__ ip_rr, const int* __restrict__ ids_rr, const int* __restrict__ dst_rr,
    __hip_bfloat16* __restrict__ mean_agg, int N) {
    int wid = (int)((blockIdx.x * 256 + threadIdx.x) >> 6);
    int lane = threadIdx.x & 63;
    if (wid >= N) return;
    float accx = 0.f, accy = 0.f;
    int cnt = 0;
    for (int side = 0; side < 2; side++) {
        const int* ip  = side ? ip_rr  : ip_ee;
        const int* ids = side ? ids_rr : ids_ee;
        const int* dst = side ? dst_rr : dst_ee;
        int s0 = ip[wid], s1 = ip[wid + 1];
        cnt += s1 - s0;
        for (int i = s0; i < s1; i++) {
            int id = ids[i];
            const __hip_bfloat162* xr = (const __hip_bfloat162*)(X + (size_t)dst[id] * D);
            __hip_bfloat162 xv = xr[lane];
            accx += __bfloat162float(xv.x);
            accy += __bfloat162float(xv.y);
        }
    }
    float inv = 1.f / fmaxf((float)cnt, 1.f);
    __hip_bfloat162 ov;
    ov.x = __float2bfloat16(accx * inv);
    ov.y = __float2bfloat16(accy * inv);
    ((__hip_bfloat162*)(mean_agg + (size_t)wid * D))[lane] = ov;
}

extern "C" void kernel_launch(void* const* d_in, const int* in_sizes, int n_in,
                              void* d_out, int out_size, void* d_ws, size_t ws_size,
                              hipStream_t stream) {
    const int* er_src = (const int*)d_in[15];
    const int* er_dst = (const int*)d_in[16];
    const int* ee_src = (const int*)d_in[17];
    const int* ee_dst = (const int*)d_in[18];
    const int* rr_src = (const int*)d_in[19];
    const int* rr_dst = (const int*)d_in[20];

    int N   = in_sizes[0] / D;
    int Eer = in_sizes[15];
    int Eee = in_sizes[17];
    int Err = in_sizes[19];

    char* ws = (char*)d_ws;
    size_t off = 0;
    auto alloc = [&](size_t bytes) -> void* {
        void* p = ws + off;
        off = (off + bytes + 255) & ~(size_t)255;
        return p;
    };
    int* flag   = (int*)alloc(256);
    int* ids_es = (int*)alloc((size_t)Eer * 4);
    int* ids_rd = (int*)alloc((size_t)Eer * 4);
    int* ids_ee = (int*)alloc((size_t)Eee * 4);
    int* ids_rr = (int*)alloc((size_t)Err * 4);
    int* indptr = (int*)alloc((size_t)4 * (N + 1) * 4);
    int* degcur = (int*)alloc((size_t)4 * N * 4);
    float* eij_e = (float*)alloc((size_t)Eer * 4);
    float* eij_r = (float*)alloc((size_t)Eer * 4);
    __hip_bfloat16* Xc = (__hip_bfloat16*)alloc((size_t)N * D * 2);
    __hip_bfloat16* part0 = (__hip_bfloat16*)alloc((size_t)N * D * 2);
    __hip_bfloat16* part1 = (__hip_bfloat16*)alloc((size_t)N * D * 2);
    __hip_bfloat16* attn_agg = part0;  // parts die after 2nd edge_score
    __hip_bfloat16* mean_agg = part1;
    unsigned short* WtA = (unsigned short*)alloc((size_t)256 * 128 * 2);
    unsigned short* WtR = (unsigned short*)alloc((size_t)256 * 128 * 2);
    unsigned short* Wt1 = (unsigned short*)alloc((size_t)128 * 128 * 2);
    unsigned short* Wt2 = (unsigned short*)alloc((size_t)128 * 128 * 2);
    unsigned short* Wt3 = (unsigned short*)alloc((size_t)128 * 128 * 2);
    // canonical bf16 copies of small params (biases + score vectors)
    ConvBatch cb;
    int widx[14] = {1, 2, 3, 4, 5, 6, 7, 8, 9, 10, 11, 12, 13, 14};
    for (int i = 0; i < 14; i++) {
        cb.src[i] = d_in[widx[i]];
        cb.n[i] = in_sizes[widx[i]];
        cb.dst[i] = (__hip_bfloat16*)alloc((size_t)cb.n[i] * 2);
    }
    const __hip_bfloat16* bae = cb.dst[1];
    const __hip_bfloat16* w0w = cb.dst[2];
    const __hip_bfloat16* w0b = cb.dst[3];
    const __hip_bfloat16* bar_= cb.dst[5];
    const __hip_bfloat16* w1w = cb.dst[6];
    const __hip_bfloat16* w1b = cb.dst[7];
    const __hip_bfloat16* b1  = cb.dst[9];
    const __hip_bfloat16* b2  = cb.dst[11];
    const __hip_bfloat16* b3  = cb.dst[13];
    (void)n_in; (void)out_size;
    if (off > ws_size) return;  // diagnostic: zeros => absmax ~2.58, not NaN

    // ---- dtype detect + canonicalize ----
    detect_kernel<<<1, 256, 0, stream>>>((const unsigned short*)d_in[0], flag);
    conv_weights_kernel<<<14, 256, 0, stream>>>(cb, flag);
    conv_x_kernel<<<(N * D + 255) / 256, 256, 0, stream>>>(d_in[0], Xc, N * D, flag);
    TransBatch tb;
    tb.base[0] = d_in[1];  tb.off[0] = 0;         tb.dst[0] = WtA;
    tb.base[1] = d_in[1];  tb.off[1] = 128 * 128; tb.dst[1] = WtA + 128 * 128;
    tb.base[2] = d_in[5];  tb.off[2] = 0;         tb.dst[2] = WtR;
    tb.base[3] = d_in[5];  tb.off[3] = 128 * 128; tb.dst[3] = WtR + 128 * 128;
    tb.base[4] = d_in[9];  tb.off[4] = 0;         tb.dst[4] = Wt1;
    tb.base[5] = d_in[11]; tb.off[5] = 0;         tb.dst[5] = Wt2;
    tb.base[6] = d_in[13]; tb.off[6] = 0;         tb.dst[6] = Wt3;
    trans_kernel<<<7, 256, 0, stream>>>(tb, flag);

    // ---- CSR build (4 keys: er_src, er_dst, ee_src, rr_src) ----
    zero_kernel<<<(4 * N + 255) / 256, 256, 0, stream>>>(degcur, 4 * N);
    count_kernel<<<(Eer + 255) / 256, 256, 0, stream>>>(er_src, Eer, degcur);
    count_kernel<<<(Eer + 255) / 256, 256, 0, stream>>>(er_dst, Eer, degcur + N);
    count_kernel<<<(Eee + 255) / 256, 256, 0, stream>>>(ee_src, Eee, degcur + 2 * N);
    count_kernel<<<(Err + 255) / 256, 256, 0, stream>>>(rr_src, Err, degcur + 3 * N);
    scan_kernel<<<4, 256, 0, stream>>>(degcur, indptr, N);
    scatter_kernel<<<(Eer + 255) / 256, 256, 0, stream>>>(er_src, Eer, degcur, ids_es);
    scatter_kernel<<<(Eer + 255) / 256, 256, 0, stream>>>(er_dst, Eer, degcur + N, ids_rd);
    scatter_kernel<<<(Eee + 255) / 256, 256, 0, stream>>>(ee_src, Eee, degcur + 2 * N, ids_ee);
    scatter_kernel<<<(Err + 255) / 256, 256, 0, stream>>>(rr_src, Err, degcur + 3 * N, ids_rr);

    int GB = (N + 63) / 64;
    int EW = (Eer + 3) / 4;  // one wave per edge

    // entity side: pair=[r,h]@Wae; key=src(h part,+bae), oth=dst(r part)
    gemm2_mfma_kernel<<<GB, 256, 0, stream>>>(Xc, WtA, bae, part0, part1, N);
    edge_score_kernel<<<EW, 256, 0, stream>>>(part1, part0, er_src, er_dst, w0w, w0b, eij_e, Eer);

    // relation side: pair=[h,r]@War; key=dst(r part,+bar), oth=src(h part)
    gemm2_mfma_kernel<<<GB, 256, 0, stream>>>(Xc, WtR, bar_, part0, part1, N);
    edge_score_kernel<<<EW, 256, 0, stream>>>(part1, part0, er_dst, er_src, w1w, w1b, eij_r, Eer);

    int NW = (N + 3) / 4;  // one wave per node
    attn_node_kernel<<<NW, 256, 0, stream>>>(Xc, eij_e, indptr, ids_es, er_dst,
                                             eij_r, indptr + (N + 1), ids_rd, er_src,
                                             attn_agg, N);
    mean_node_kernel<<<NW, 256, 0, stream>>>(Xc, indptr + 2 * (N + 1), ids_ee, ee_dst,
                                             indptr + 3 * (N + 1), ids_rr, rr_dst,
                                             mean_agg, N);
    final_mfma_kernel<<<GB, 256, 0, stream>>>(Xc, attn_agg, mean_agg,
                                              Wt1, b1, Wt2, b2, Wt3, b3,
                                              d_out, flag, N);
}

// Round 5
// 1133.128 us; speedup vs baseline: 1.6019x; 1.1916x over previous
//
#include <hip/hip_runtime.h>
#include <hip/hip_bf16.h>

#define D 128
#define TILE 2048

typedef __bf16 bf16x8 __attribute__((ext_vector_type(8)));
typedef float f32x4 __attribute__((ext_vector_type(4)));

// ---- dtype detection: are float inputs f32 or bf16 on device? flag=1 => f32.
__global__ __launch_bounds__(256) void detect_kernel(const unsigned short* __restrict__ x,
                                                     int* __restrict__ flag) {
    int t = threadIdx.x;
    int cnt = 0;
    for (int i = t; i < 4096; i += 256) {
        unsigned e = (x[i] >> 7) & 0xFFu;
        if (e == 0xFFu || e >= 0x90u || (e >= 1u && e <= 0x6Eu)) cnt++;
    }
    __shared__ int sh[256];
    sh[t] = cnt;
    __syncthreads();
    for (int off = 128; off; off >>= 1) {
        if (t < off) sh[t] += sh[t + off];
        __syncthreads();
    }
    if (t == 0) flag[0] = (sh[0] > 800) ? 1 : 0;
}

struct ConvBatch {
    const void* src[14];
    __hip_bfloat16* dst[14];
    int n[14];
};

__global__ __launch_bounds__(256) void conv_weights_kernel(ConvBatch cb,
                                                           const int* __restrict__ flag) {
    int a = blockIdx.x;
    const void* s = cb.src[a];
    __hip_bfloat16* d = cb.dst[a];
    int n = cb.n[a];
    int f = flag[0];
    for (int i = threadIdx.x; i < n; i += 256) {
        d[i] = f ? __float2bfloat16(((const float*)s)[i])
                 : ((const __hip_bfloat16*)s)[i];
    }
}

__global__ __launch_bounds__(256) void conv_x_kernel(const void* __restrict__ src,
                                                     __hip_bfloat16* __restrict__ dst,
                                                     int n, const int* __restrict__ flag) {
    int i = blockIdx.x * 256 + threadIdx.x;
    int f = flag[0];
    if (i < n)
        dst[i] = f ? __float2bfloat16(((const float*)src)[i])
                   : ((const __hip_bfloat16*)src)[i];
}

// ---- weight transpose: 7 independent 128x128 blocks -> Wt[c][k] = W[k][c] (bf16)
struct TransBatch {
    const void* base[7];
    int off[7];
    unsigned short* dst[7];
};

__global__ __launch_bounds__(256) void trans_kernel(TransBatch tb,
                                                    const int* __restrict__ flag) {
    int a = blockIdx.x;
    int f = flag[0];
    const float* sf = (const float*)tb.base[a] + tb.off[a];
    const unsigned short* sb = (const unsigned short*)tb.base[a] + tb.off[a];
    unsigned short* d = tb.dst[a];
    for (int idx = threadIdx.x; idx < 128 * 128; idx += 256) {
        int k = idx >> 7, c = idx & 127;
        __hip_bfloat16 v;
        if (f) v = __float2bfloat16(sf[idx]);
        else   v = *(const __hip_bfloat16*)&sb[idx];
        d[c * 128 + k] = *(unsigned short*)&v;
    }
}

__global__ __launch_bounds__(256) void zero_kernel(int* p, int n) {
    int i = blockIdx.x * 256 + threadIdx.x;
    if (i < n) p[i] = 0;
}

__global__ __launch_bounds__(256) void count_kernel(const int* __restrict__ keys, int E,
                                                    int* __restrict__ deg) {
    int i = blockIdx.x * 256 + threadIdx.x;
    if (i < E) atomicAdd(&deg[keys[i]], 1);
}

// ---- hierarchical scan, phase 1: per-tile sums. grid = 4 * ntpa blocks.
__global__ __launch_bounds__(256) void scan_partial_kernel(const int* __restrict__ deg,
                                                           int* __restrict__ tsum,
                                                           int N, int ntpa) {
    int a = blockIdx.x / ntpa, t = blockIdx.x % ntpa;
    const int* d = deg + (size_t)a * N + (size_t)t * TILE;
    int lim = N - t * TILE; if (lim > TILE) lim = TILE;
    int base = threadIdx.x * 8;
    int s = 0;
#pragma unroll
    for (int j = 0; j < 8; j++) {
        int i = base + j;
        if (i < lim) s += d[i];
    }
    __shared__ int sh[256];
    sh[threadIdx.x] = s;
    __syncthreads();
    for (int off = 128; off; off >>= 1) {
        if (threadIdx.x < off) sh[threadIdx.x] += sh[threadIdx.x + off];
        __syncthreads();
    }
    if (threadIdx.x == 0) tsum[blockIdx.x] = sh[0];
}

// ---- phase 2: exclusive scan of tile sums per array (ntpa <= 256); one block.
__global__ __launch_bounds__(256) void scan_tiles_kernel(const int* __restrict__ tsum,
                                                         int* __restrict__ toff,
                                                         int* __restrict__ indptr,
                                                         int N, int ntpa) {
    __shared__ int tmp[256];
    int t = threadIdx.x;
    for (int a = 0; a < 4; a++) {
        int v = (t < ntpa) ? tsum[a * ntpa + t] : 0;
        tmp[t] = v;
        __syncthreads();
        for (int off = 1; off < 256; off <<= 1) {
            int u = (t >= off) ? tmp[t - off] : 0;
            __syncthreads();
            tmp[t] += u;
            __syncthreads();
        }
        if (t < ntpa) toff[a * ntpa + t] = tmp[t] - v;  // exclusive
        if (t == ntpa - 1) indptr[(size_t)a * (N + 1) + N] = tmp[t];
        __syncthreads();
    }
}

// ---- phase 3: intra-tile scan + tile offset; writes indptr and cursor.
// cursor overwrites degcur in place (reads first, then writes).
__global__ __launch_bounds__(256) void scan_final_kernel(int* __restrict__ degcur,
                                                         const int* __restrict__ toff,
                                                         int* __restrict__ indptr,
                                                         int N, int ntpa) {
    int a = blockIdx.x / ntpa, t = blockIdx.x % ntpa;
    int* d = degcur + (size_t)a * N + (size_t)t * TILE;
    int* ip = indptr + (size_t)a * (N + 1) + (size_t)t * TILE;
    int lim = N - t * TILE; if (lim > TILE) lim = TILE;
    int base = threadIdx.x * 8;
    int v[8];
    int s = 0;
#pragma unroll
    for (int j = 0; j < 8; j++) {
        int i = base + j;
        v[j] = (i < lim) ? d[i] : 0;
        s += v[j];
    }
    __shared__ int tmp[256];
    tmp[threadIdx.x] = s;
    __syncthreads();
    for (int off = 1; off < 256; off <<= 1) {
        int u = (threadIdx.x >= off) ? tmp[threadIdx.x - off] : 0;
        __syncthreads();
        tmp[threadIdx.x] += u;
        __syncthreads();
    }
    int run = toff[blockIdx.x] + tmp[threadIdx.x] - s;
#pragma unroll
    for (int j = 0; j < 8; j++) {
        int i = base + j;
        if (i < lim) { ip[i] = run; d[i] = run; run += v[j]; }
    }
}

__global__ __launch_bounds__(256) void scatter_kernel(const int* __restrict__ keys, int E,
                                                      int* __restrict__ cursor,
                                                      int* __restrict__ ids) {
    int i = blockIdx.x * 256 + threadIdx.x;
    if (i < E) {
        int p = atomicAdd(&cursor[keys[i]], 1);
        ids[p] = i;
    }
}

// ---- MFMA GEMM: parts[n] = X[n] @ {Wt rows 0..127 | 128..255}^T (+bias on part1)
__global__ __launch_bounds__(256) void gemm2_mfma_kernel(
    const __hip_bfloat16* __restrict__ X,
    const unsigned short* __restrict__ Wt,      // 256 x 128, Wt[c][k]
    const __hip_bfloat16* __restrict__ bias,    // 128 (part1 only)
    __hip_bfloat16* __restrict__ part0,
    __hip_bfloat16* __restrict__ part1, int N) {
    __shared__ __align__(16) unsigned short As[64 * 136];
    int n0 = blockIdx.x * 64;
    for (int idx = threadIdx.x; idx < 64 * 16; idx += 256) {
        int r = idx >> 4, ch = idx & 15;
        uint4 v = make_uint4(0u, 0u, 0u, 0u);
        int n = n0 + r;
        if (n < N) v = ((const uint4*)(X + (size_t)n * D))[ch];
        *(uint4*)&As[r * 136 + ch * 8] = v;
    }
    __syncthreads();
    int w = threadIdx.x >> 6, lane = threadIdx.x & 63;
    int n15 = lane & 15, quad = lane >> 4;
    const unsigned short* arow = &As[(w * 16 + n15) * 136 + quad * 8];
    bf16x8 af[4];
#pragma unroll
    for (int t = 0; t < 4; t++) af[t] = *(const bf16x8*)(arow + t * 32);
    for (int c = 0; c < 16; c++) {
        f32x4 acc = {0.f, 0.f, 0.f, 0.f};
        const unsigned short* bbase = Wt + (size_t)(c * 16 + n15) * D + quad * 8;
#pragma unroll
        for (int t = 0; t < 4; t++)
            acc = __builtin_amdgcn_mfma_f32_16x16x32_bf16(
                af[t], *(const bf16x8*)(bbase + t * 32), acc, 0, 0, 0);
        float b;
        __hip_bfloat16* outp;
        int col;
        if (c < 8) { outp = part0; col = c * 16 + n15; b = 0.f; }
        else       { outp = part1; col = c * 16 + n15 - 128;
                     b = __bfloat162float(bias[col]); }
#pragma unroll
        for (int i = 0; i < 4; i++) {
            int row = n0 + w * 16 + quad * 4 + i;
            if (row < N) outp[(size_t)row * D + col] = __float2bfloat16(acc[i] + b);
        }
    }
}

// ---- MFMA final: out = tanh(X@W1+b1)+tanh(A@W2+b2)+tanh(M@W3+b3)
__global__ __launch_bounds__(256) void final_mfma_kernel(
    const __hip_bfloat16* __restrict__ X, const __hip_bfloat16* __restrict__ Agg,
    const __hip_bfloat16* __restrict__ Mn,
    const unsigned short* __restrict__ Wt1, const __hip_bfloat16* __restrict__ b1,
    const unsigned short* __restrict__ Wt2, const __hip_bfloat16* __restrict__ b2,
    const unsigned short* __restrict__ Wt3, const __hip_bfloat16* __restrict__ b3,
    void* __restrict__ out, const int* __restrict__ flag, int N) {
    __shared__ __align__(16) unsigned short As[64 * 136];
    int n0 = blockIdx.x * 64;
    int w = threadIdx.x >> 6, lane = threadIdx.x & 63;
    int n15 = lane & 15, quad = lane >> 4;
    float osum[8][4];
#pragma unroll
    for (int c = 0; c < 8; c++)
#pragma unroll
        for (int i = 0; i < 4; i++) osum[c][i] = 0.f;
    const __hip_bfloat16* srcs[3] = {X, Agg, Mn};
    const unsigned short* Wts[3] = {Wt1, Wt2, Wt3};
    const __hip_bfloat16* bs[3] = {b1, b2, b3};
    for (int m = 0; m < 3; m++) {
        __syncthreads();
        const __hip_bfloat16* S = srcs[m];
        for (int idx = threadIdx.x; idx < 64 * 16; idx += 256) {
            int r = idx >> 4, ch = idx & 15;
            uint4 v = make_uint4(0u, 0u, 0u, 0u);
            int n = n0 + r;
            if (n < N) v = ((const uint4*)(S + (size_t)n * D))[ch];
            *(uint4*)&As[r * 136 + ch * 8] = v;
        }
        __syncthreads();
        const unsigned short* arow = &As[(w * 16 + n15) * 136 + quad * 8];
        bf16x8 af[4];
#pragma unroll
        for (int t = 0; t < 4; t++) af[t] = *(const bf16x8*)(arow + t * 32);
        const unsigned short* Wm = Wts[m];
        for (int c = 0; c < 8; c++) {
            f32x4 acc = {0.f, 0.f, 0.f, 0.f};
            const unsigned short* bbase = Wm + (size_t)(c * 16 + n15) * D + quad * 8;
#pragma unroll
            for (int t = 0; t < 4; t++)
                acc = __builtin_amdgcn_mfma_f32_16x16x32_bf16(
                    af[t], *(const bf16x8*)(bbase + t * 32), acc, 0, 0, 0);
            float bb = __bfloat162float(bs[m][c * 16 + n15]);
#pragma unroll
            for (int i = 0; i < 4; i++) osum[c][i] += tanhf(acc[i] + bb);
        }
    }
    int f = flag[0];
    for (int c = 0; c < 8; c++) {
        int col = c * 16 + n15;
#pragma unroll
        for (int i = 0; i < 4; i++) {
            int row = n0 + w * 16 + quad * 4 + i;
            if (row < N) {
                if (f) ((float*)out)[(size_t)row * D + col] = osum[c][i];
                else   ((__hip_bfloat16*)out)[(size_t)row * D + col] =
                           __float2bfloat16(osum[c][i]);
            }
        }
    }
}

// score[e] = sum_j tanh(Pkey[key[e]][j] + Poth[oth[e]][j]) * w[j] + wb
__global__ __launch_bounds__(256) void edge_score_kernel(const __hip_bfloat16* __restrict__ Pkey,
                                                         const __hip_bfloat16* __restrict__ Poth,
                                                         const int* __restrict__ keys,
                                                         const int* __restrict__ oths,
                                                         const __hip_bfloat16* __restrict__ w,
                                                         const __hip_bfloat16* __restrict__ wb,
                                                         float* __restrict__ eij, int E) {
    int wid = (int)((blockIdx.x * 256 + threadIdx.x) >> 6);
    int lane = threadIdx.x & 63;
    if (wid >= E) return;
    int key = keys[wid], oth = oths[wid];
    const __hip_bfloat162* a = (const __hip_bfloat162*)(Pkey + (size_t)key * D);
    const __hip_bfloat162* b = (const __hip_bfloat162*)(Poth + (size_t)oth * D);
    __hip_bfloat162 av = a[lane], bv = b[lane];
    __hip_bfloat162 wv = ((const __hip_bfloat162*)w)[lane];
    float p = tanhf(__bfloat162float(av.x) + __bfloat162float(bv.x)) * __bfloat162float(wv.x)
            + tanhf(__bfloat162float(av.y) + __bfloat162float(bv.y)) * __bfloat162float(wv.y);
    for (int off = 32; off; off >>= 1) p += __shfl_xor(p, off);
    if (lane == 0) eij[wid] = p + __bfloat162float(wb[0]);
}

// One wave per node: fused segment softmax + weighted aggregation, both sides.
__global__ __launch_bounds__(256) void attn_node_kernel(
    const __hip_bfloat16* __restrict__ X,
    const float* __restrict__ eij_e, const int* __restrict__ ip_e,
    const int* __restrict__ ids_e, const int* __restrict__ oth_e,
    const float* __restrict__ eij_r, const int* __restrict__ ip_r,
    const int* __restrict__ ids_r, const int* __restrict__ oth_r,
    __hip_bfloat16* __restrict__ attn_agg, int N) {
    int wid = (int)((blockIdx.x * 256 + threadIdx.x) >> 6);
    int lane = threadIdx.x & 63;
    if (wid >= N) return;
    float accx = 0.f, accy = 0.f;
    for (int side = 0; side < 2; side++) {
        const float* eij = side ? eij_r : eij_e;
        const int* ip  = side ? ip_r  : ip_e;
        const int* ids = side ? ids_r : ids_e;
        const int* oth = side ? oth_r : oth_e;
        int s0 = ip[wid], s1 = ip[wid + 1];
        if (s1 == s0) continue;
        float m = 0.f;  // torch amax include_self over zeros => floor at 0
        for (int i = s0 + lane; i < s1; i += 64) m = fmaxf(m, eij[ids[i]]);
        for (int off = 32; off; off >>= 1) m = fmaxf(m, __shfl_xor(m, off));
        float ssum = 0.f;
        for (int i = s0 + lane; i < s1; i += 64) ssum += __expf(eij[ids[i]] - m);
        for (int off = 32; off; off >>= 1) ssum += __shfl_xor(ssum, off);
        float inv = 1.f / (ssum + 1e-9f);
        for (int i = s0; i < s1; i++) {
            int id = ids[i];
            float p = __expf(eij[id] - m) * inv;
            const __hip_bfloat162* xr = (const __hip_bfloat162*)(X + (size_t)oth[id] * D);
            __hip_bfloat162 xv = xr[lane];
            accx += p * __bfloat162float(xv.x);
            accy += p * __bfloat162float(xv.y);
        }
    }
    __hip_bfloat162 ov;
    ov.x = __float2bfloat16(accx);
    ov.y = __float2bfloat16(accy);
    ((__hip_bfloat162*)(attn_agg + (size_t)wid * D))[lane] = ov;
}

// One wave per node: mean over ee- and rr-neighbours.
__global__ __launch_bounds__(256) void mean_node_kernel(
    const __hip_bfloat16* __restrict__ X,
    const int* __restrict__ ip_ee, const int* __restrict__ ids_ee, const int* __restrict__ dst_ee,
    const int* __restrict__ ip_rr, const int* __restrict__ ids_rr, const int* __restrict__ dst_rr,
    __hip_bfloat16* __restrict__ mean_agg, int N) {
    int wid = (int)((blockIdx.x * 256 + threadIdx.x) >> 6);
    int lane = threadIdx.x & 63;
    if (wid >= N) return;
    float accx = 0.f, accy = 0.f;
    int cnt = 0;
    for (int side = 0; side < 2; side++) {
        const int* ip  = side ? ip_rr  : ip_ee;
        const int* ids = side ? ids_rr : ids_ee;
        const int* dst = side ? dst_rr : dst_ee;
        int s0 = ip[wid], s1 = ip[wid + 1];
        cnt += s1 - s0;
        for (int i = s0; i < s1; i++) {
            int id = ids[i];
            const __hip_bfloat162* xr = (const __hip_bfloat162*)(X + (size_t)dst[id] * D);
            __hip_bfloat162 xv = xr[lane];
            accx += __bfloat162float(xv.x);
            accy += __bfloat162float(xv.y);
        }
    }
    float inv = 1.f / fmaxf((float)cnt, 1.f);
    __hip_bfloat162 ov;
    ov.x = __float2bfloat16(accx * inv);
    ov.y = __float2bfloat16(accy * inv);
    ((__hip_bfloat162*)(mean_agg + (size_t)wid * D))[lane] = ov;
}

extern "C" void kernel_launch(void* const* d_in, const int* in_sizes, int n_in,
                              void* d_out, int out_size, void* d_ws, size_t ws_size,
                              hipStream_t stream) {
    const int* er_src = (const int*)d_in[15];
    const int* er_dst = (const int*)d_in[16];
    const int* ee_src = (const int*)d_in[17];
    const int* ee_dst = (const int*)d_in[18];
    const int* rr_src = (const int*)d_in[19];
    const int* rr_dst = (const int*)d_in[20];

    int N   = in_sizes[0] / D;
    int Eer = in_sizes[15];
    int Eee = in_sizes[17];
    int Err = in_sizes[19];

    char* ws = (char*)d_ws;
    size_t off = 0;
    auto alloc = [&](size_t bytes) -> void* {
        void* p = ws + off;
        off = (off + bytes + 255) & ~(size_t)255;
        return p;
    };
    int ntpa = (N + TILE - 1) / TILE;     // tiles per array (<=256 for N<=524288)
    int T = 4 * ntpa;
    int* flag   = (int*)alloc(256);
    int* ids_es = (int*)alloc((size_t)Eer * 4);
    int* ids_rd = (int*)alloc((size_t)Eer * 4);
    int* ids_ee = (int*)alloc((size_t)Eee * 4);
    int* ids_rr = (int*)alloc((size_t)Err * 4);
    int* indptr = (int*)alloc((size_t)4 * (N + 1) * 4);
    int* degcur = (int*)alloc((size_t)4 * N * 4);
    int* tsum   = (int*)alloc((size_t)T * 4);
    int* toff   = (int*)alloc((size_t)T * 4);
    float* eij_e = (float*)alloc((size_t)Eer * 4);
    float* eij_r = (float*)alloc((size_t)Eer * 4);
    __hip_bfloat16* Xc = (__hip_bfloat16*)alloc((size_t)N * D * 2);
    __hip_bfloat16* part0 = (__hip_bfloat16*)alloc((size_t)N * D * 2);
    __hip_bfloat16* part1 = (__hip_bfloat16*)alloc((size_t)N * D * 2);
    __hip_bfloat16* attn_agg = part0;  // parts die after 2nd edge_score
    __hip_bfloat16* mean_agg = part1;
    unsigned short* WtA = (unsigned short*)alloc((size_t)256 * 128 * 2);
    unsigned short* WtR = (unsigned short*)alloc((size_t)256 * 128 * 2);
    unsigned short* Wt1 = (unsigned short*)alloc((size_t)128 * 128 * 2);
    unsigned short* Wt2 = (unsigned short*)alloc((size_t)128 * 128 * 2);
    unsigned short* Wt3 = (unsigned short*)alloc((size_t)128 * 128 * 2);
    ConvBatch cb;
    int widx[14] = {1, 2, 3, 4, 5, 6, 7, 8, 9, 10, 11, 12, 13, 14};
    for (int i = 0; i < 14; i++) {
        cb.src[i] = d_in[widx[i]];
        cb.n[i] = in_sizes[widx[i]];
        cb.dst[i] = (__hip_bfloat16*)alloc((size_t)cb.n[i] * 2);
    }
    const __hip_bfloat16* bae = cb.dst[1];
    const __hip_bfloat16* w0w = cb.dst[2];
    const __hip_bfloat16* w0b = cb.dst[3];
    const __hip_bfloat16* bar_= cb.dst[5];
    const __hip_bfloat16* w1w = cb.dst[6];
    const __hip_bfloat16* w1b = cb.dst[7];
    const __hip_bfloat16* b1  = cb.dst[9];
    const __hip_bfloat16* b2  = cb.dst[11];
    const __hip_bfloat16* b3  = cb.dst[13];
    (void)n_in; (void)out_size;
    if (off > ws_size) return;  // diagnostic: zeros => absmax ~2.58, not NaN

    // ---- dtype detect + canonicalize ----
    detect_kernel<<<1, 256, 0, stream>>>((const unsigned short*)d_in[0], flag);
    conv_weights_kernel<<<14, 256, 0, stream>>>(cb, flag);
    conv_x_kernel<<<(N * D + 255) / 256, 256, 0, stream>>>(d_in[0], Xc, N * D, flag);
    TransBatch tb;
    tb.base[0] = d_in[1];  tb.off[0] = 0;         tb.dst[0] = WtA;
    tb.base[1] = d_in[1];  tb.off[1] = 128 * 128; tb.dst[1] = WtA + 128 * 128;
    tb.base[2] = d_in[5];  tb.off[2] = 0;         tb.dst[2] = WtR;
    tb.base[3] = d_in[5];  tb.off[3] = 128 * 128; tb.dst[3] = WtR + 128 * 128;
    tb.base[4] = d_in[9];  tb.off[4] = 0;         tb.dst[4] = Wt1;
    tb.base[5] = d_in[11]; tb.off[5] = 0;         tb.dst[5] = Wt2;
    tb.base[6] = d_in[13]; tb.off[6] = 0;         tb.dst[6] = Wt3;
    trans_kernel<<<7, 256, 0, stream>>>(tb, flag);

    // ---- CSR build (4 keys: er_src, er_dst, ee_src, rr_src) ----
    zero_kernel<<<(4 * N + 255) / 256, 256, 0, stream>>>(degcur, 4 * N);
    count_kernel<<<(Eer + 255) / 256, 256, 0, stream>>>(er_src, Eer, degcur);
    count_kernel<<<(Eer + 255) / 256, 256, 0, stream>>>(er_dst, Eer, degcur + N);
    count_kernel<<<(Eee + 255) / 256, 256, 0, stream>>>(ee_src, Eee, degcur + 2 * N);
    count_kernel<<<(Err + 255) / 256, 256, 0, stream>>>(rr_src, Err, degcur + 3 * N);
    scan_partial_kernel<<<T, 256, 0, stream>>>(degcur, tsum, N, ntpa);
    scan_tiles_kernel<<<1, 256, 0, stream>>>(tsum, toff, indptr, N, ntpa);
    scan_final_kernel<<<T, 256, 0, stream>>>(degcur, toff, indptr, N, ntpa);
    scatter_kernel<<<(Eer + 255) / 256, 256, 0, stream>>>(er_src, Eer, degcur, ids_es);
    scatter_kernel<<<(Eer + 255) / 256, 256, 0, stream>>>(er_dst, Eer, degcur + N, ids_rd);
    scatter_kernel<<<(Eee + 255) / 256, 256, 0, stream>>>(ee_src, Eee, degcur + 2 * N, ids_ee);
    scatter_kernel<<<(Err + 255) / 256, 256, 0, stream>>>(rr_src, Err, degcur + 3 * N, ids_rr);

    int GB = (N + 63) / 64;
    int EW = (Eer + 3) / 4;  // one wave per edge

    // entity side: pair=[r,h]@Wae; key=src(h part,+bae), oth=dst(r part)
    gemm2_mfma_kernel<<<GB, 256, 0, stream>>>(Xc, WtA, bae, part0, part1, N);
    edge_score_kernel<<<EW, 256, 0, stream>>>(part1, part0, er_src, er_dst, w0w, w0b, eij_e, Eer);

    // relation side: pair=[h,r]@War; key=dst(r part,+bar), oth=src(h part)
    gemm2_mfma_kernel<<<GB, 256, 0, stream>>>(Xc, WtR, bar_, part0, part1, N);
    edge_score_kernel<<<EW, 256, 0, stream>>>(part1, part0, er_dst, er_src, w1w, w1b, eij_r, Eer);

    int NW = (N + 3) / 4;  // one wave per node
    attn_node_kernel<<<NW, 256, 0, stream>>>(Xc, eij_e, indptr, ids_es, er_dst,
                                             eij_r, indptr + (N + 1), ids_rd, er_src,
                                             attn_agg, N);
    mean_node_kernel<<<NW, 256, 0, stream>>>(Xc, indptr + 2 * (N + 1), ids_ee, ee_dst,
                                             indptr + 3 * (N + 1), ids_rr, rr_dst,
                                             mean_agg, N);
    final_mfma_kernel<<<GB, 256, 0, stream>>>(Xc, attn_agg, mean_agg,
                                              Wt1, b1, Wt2, b2, Wt3, b3,
                                              d_out, flag, N);
}

// Round 6
// 1007.706 us; speedup vs baseline: 1.8013x; 1.1245x over previous
//
#include <hip/hip_runtime.h>
#include <hip/hip_bf16.h>

#define D 128
#define TILE 2048

typedef __bf16 bf16x8 __attribute__((ext_vector_type(8)));
typedef float f32x4 __attribute__((ext_vector_type(4)));

// ---- dtype detection: are float inputs f32 or bf16 on device? flag=1 => f32.
__global__ __launch_bounds__(256) void detect_kernel(const unsigned short* __restrict__ x,
                                                     int* __restrict__ flag) {
    int t = threadIdx.x;
    int cnt = 0;
    for (int i = t; i < 4096; i += 256) {
        unsigned e = (x[i] >> 7) & 0xFFu;
        if (e == 0xFFu || e >= 0x90u || (e >= 1u && e <= 0x6Eu)) cnt++;
    }
    __shared__ int sh[256];
    sh[t] = cnt;
    __syncthreads();
    for (int off = 128; off; off >>= 1) {
        if (t < off) sh[t] += sh[t + off];
        __syncthreads();
    }
    if (t == 0) flag[0] = (sh[0] > 800) ? 1 : 0;
}

struct ConvBatch {
    const void* src[14];
    __hip_bfloat16* dst[14];
    int n[14];
};

__global__ __launch_bounds__(256) void conv_weights_kernel(ConvBatch cb,
                                                           const int* __restrict__ flag) {
    int a = blockIdx.x;
    const void* s = cb.src[a];
    __hip_bfloat16* d = cb.dst[a];
    int n = cb.n[a];
    int f = flag[0];
    for (int i = threadIdx.x; i < n; i += 256) {
        d[i] = f ? __float2bfloat16(((const float*)s)[i])
                 : ((const __hip_bfloat16*)s)[i];
    }
}

__global__ __launch_bounds__(256) void conv_x_kernel(const void* __restrict__ src,
                                                     __hip_bfloat16* __restrict__ dst,
                                                     int n, const int* __restrict__ flag) {
    int i = blockIdx.x * 256 + threadIdx.x;
    int f = flag[0];
    if (i < n)
        dst[i] = f ? __float2bfloat16(((const float*)src)[i])
                   : ((const __hip_bfloat16*)src)[i];
}

// ---- weight transpose: 7 independent 128x128 blocks -> Wt[c][k] = W[k][c] (bf16)
struct TransBatch {
    const void* base[7];
    int off[7];
    unsigned short* dst[7];
};

__global__ __launch_bounds__(256) void trans_kernel(TransBatch tb,
                                                    const int* __restrict__ flag) {
    int a = blockIdx.x;
    int f = flag[0];
    const float* sf = (const float*)tb.base[a] + tb.off[a];
    const unsigned short* sb = (const unsigned short*)tb.base[a] + tb.off[a];
    unsigned short* d = tb.dst[a];
    for (int idx = threadIdx.x; idx < 128 * 128; idx += 256) {
        int k = idx >> 7, c = idx & 127;
        __hip_bfloat16 v;
        if (f) v = __float2bfloat16(sf[idx]);
        else   v = *(const __hip_bfloat16*)&sb[idx];
        d[c * 128 + k] = *(unsigned short*)&v;
    }
}

__global__ __launch_bounds__(256) void zero_kernel(int* p, int n) {
    int i = blockIdx.x * 256 + threadIdx.x;
    if (i < n) p[i] = 0;
}

__global__ __launch_bounds__(256) void count_kernel(const int* __restrict__ keys, int E,
                                                    int* __restrict__ deg) {
    int i = blockIdx.x * 256 + threadIdx.x;
    if (i < E) atomicAdd(&deg[keys[i]], 1);
}

// ---- hierarchical scan, phase 1: per-tile sums. grid = 4 * ntpa blocks.
__global__ __launch_bounds__(256) void scan_partial_kernel(const int* __restrict__ deg,
                                                           int* __restrict__ tsum,
                                                           int N, int ntpa) {
    int a = blockIdx.x / ntpa, t = blockIdx.x % ntpa;
    const int* d = deg + (size_t)a * N + (size_t)t * TILE;
    int lim = N - t * TILE; if (lim > TILE) lim = TILE;
    int base = threadIdx.x * 8;
    int s = 0;
#pragma unroll
    for (int j = 0; j < 8; j++) {
        int i = base + j;
        if (i < lim) s += d[i];
    }
    __shared__ int sh[256];
    sh[threadIdx.x] = s;
    __syncthreads();
    for (int off = 128; off; off >>= 1) {
        if (threadIdx.x < off) sh[threadIdx.x] += sh[threadIdx.x + off];
        __syncthreads();
    }
    if (threadIdx.x == 0) tsum[blockIdx.x] = sh[0];
}

// ---- phase 2: exclusive scan of tile sums per array (ntpa <= 256); one block.
__global__ __launch_bounds__(256) void scan_tiles_kernel(const int* __restrict__ tsum,
                                                         int* __restrict__ toff,
                                                         int* __restrict__ indptr,
                                                         int N, int ntpa) {
    __shared__ int tmp[256];
    int t = threadIdx.x;
    for (int a = 0; a < 4; a++) {
        int v = (t < ntpa) ? tsum[a * ntpa + t] : 0;
        tmp[t] = v;
        __syncthreads();
        for (int off = 1; off < 256; off <<= 1) {
            int u = (t >= off) ? tmp[t - off] : 0;
            __syncthreads();
            tmp[t] += u;
            __syncthreads();
        }
        if (t < ntpa) toff[a * ntpa + t] = tmp[t] - v;  // exclusive
        if (t == ntpa - 1) indptr[(size_t)a * (N + 1) + N] = tmp[t];
        __syncthreads();
    }
}

// ---- phase 3: intra-tile scan + tile offset; writes indptr and cursor.
__global__ __launch_bounds__(256) void scan_final_kernel(int* __restrict__ degcur,
                                                         const int* __restrict__ toff,
                                                         int* __restrict__ indptr,
                                                         int N, int ntpa) {
    int a = blockIdx.x / ntpa, t = blockIdx.x % ntpa;
    int* d = degcur + (size_t)a * N + (size_t)t * TILE;
    int* ip = indptr + (size_t)a * (N + 1) + (size_t)t * TILE;
    int lim = N - t * TILE; if (lim > TILE) lim = TILE;
    int base = threadIdx.x * 8;
    int v[8];
    int s = 0;
#pragma unroll
    for (int j = 0; j < 8; j++) {
        int i = base + j;
        v[j] = (i < lim) ? d[i] : 0;
        s += v[j];
    }
    __shared__ int tmp[256];
    tmp[threadIdx.x] = s;
    __syncthreads();
    for (int off = 1; off < 256; off <<= 1) {
        int u = (threadIdx.x >= off) ? tmp[threadIdx.x - off] : 0;
        __syncthreads();
        tmp[threadIdx.x] += u;
        __syncthreads();
    }
    int run = toff[blockIdx.x] + tmp[threadIdx.x] - s;
#pragma unroll
    for (int j = 0; j < 8; j++) {
        int i = base + j;
        if (i < lim) { ip[i] = run; d[i] = run; run += v[j]; }
    }
}

// attention sides: record CSR slot pos[e] and scatter the gather-index directly.
__global__ __launch_bounds__(256) void scatter_attn_kernel(const int* __restrict__ keys,
                                                           const int* __restrict__ oths, int E,
                                                           int* __restrict__ cursor,
                                                           int* __restrict__ pos,
                                                           int* __restrict__ oth_sorted) {
    int i = blockIdx.x * 256 + threadIdx.x;
    if (i < E) {
        int p = atomicAdd(&cursor[keys[i]], 1);
        pos[i] = p;
        oth_sorted[p] = oths[i];
    }
}

// mean sides: only the sorted gather-index is needed.
__global__ __launch_bounds__(256) void scatter_mean_kernel(const int* __restrict__ keys,
                                                           const int* __restrict__ dsts, int E,
                                                           int* __restrict__ cursor,
                                                           int* __restrict__ dst_sorted) {
    int i = blockIdx.x * 256 + threadIdx.x;
    if (i < E) {
        int p = atomicAdd(&cursor[keys[i]], 1);
        dst_sorted[p] = dsts[i];
    }
}

// ---- MFMA GEMM: parts[n] = X[n] @ {Wt rows 0..127 | 128..255}^T (+bias on part1)
__global__ __launch_bounds__(256) void gemm2_mfma_kernel(
    const __hip_bfloat16* __restrict__ X,
    const unsigned short* __restrict__ Wt,      // 256 x 128, Wt[c][k]
    const __hip_bfloat16* __restrict__ bias,    // 128 (part1 only)
    __hip_bfloat16* __restrict__ part0,
    __hip_bfloat16* __restrict__ part1, int N) {
    __shared__ __align__(16) unsigned short As[64 * 136];
    int n0 = blockIdx.x * 64;
    for (int idx = threadIdx.x; idx < 64 * 16; idx += 256) {
        int r = idx >> 4, ch = idx & 15;
        uint4 v = make_uint4(0u, 0u, 0u, 0u);
        int n = n0 + r;
        if (n < N) v = ((const uint4*)(X + (size_t)n * D))[ch];
        *(uint4*)&As[r * 136 + ch * 8] = v;
    }
    __syncthreads();
    int w = threadIdx.x >> 6, lane = threadIdx.x & 63;
    int n15 = lane & 15, quad = lane >> 4;
    const unsigned short* arow = &As[(w * 16 + n15) * 136 + quad * 8];
    bf16x8 af[4];
#pragma unroll
    for (int t = 0; t < 4; t++) af[t] = *(const bf16x8*)(arow + t * 32);
    for (int c = 0; c < 16; c++) {
        f32x4 acc = {0.f, 0.f, 0.f, 0.f};
        const unsigned short* bbase = Wt + (size_t)(c * 16 + n15) * D + quad * 8;
#pragma unroll
        for (int t = 0; t < 4; t++)
            acc = __builtin_amdgcn_mfma_f32_16x16x32_bf16(
                af[t], *(const bf16x8*)(bbase + t * 32), acc, 0, 0, 0);
        float b;
        __hip_bfloat16* outp;
        int col;
        if (c < 8) { outp = part0; col = c * 16 + n15; b = 0.f; }
        else       { outp = part1; col = c * 16 + n15 - 128;
                     b = __bfloat162float(bias[col]); }
#pragma unroll
        for (int i = 0; i < 4; i++) {
            int row = n0 + w * 16 + quad * 4 + i;
            if (row < N) outp[(size_t)row * D + col] = __float2bfloat16(acc[i] + b);
        }
    }
}

// ---- MFMA final: out = tanh(X@W1+b1)+tanh(A@W2+b2)+tanh(M@W3+b3)
__global__ __launch_bounds__(256) void final_mfma_kernel(
    const __hip_bfloat16* __restrict__ X, const __hip_bfloat16* __restrict__ Agg,
    const __hip_bfloat16* __restrict__ Mn,
    const unsigned short* __restrict__ Wt1, const __hip_bfloat16* __restrict__ b1,
    const unsigned short* __restrict__ Wt2, const __hip_bfloat16* __restrict__ b2,
    const unsigned short* __restrict__ Wt3, const __hip_bfloat16* __restrict__ b3,
    void* __restrict__ out, const int* __restrict__ flag, int N) {
    __shared__ __align__(16) unsigned short As[64 * 136];
    int n0 = blockIdx.x * 64;
    int w = threadIdx.x >> 6, lane = threadIdx.x & 63;
    int n15 = lane & 15, quad = lane >> 4;
    float osum[8][4];
#pragma unroll
    for (int c = 0; c < 8; c++)
#pragma unroll
        for (int i = 0; i < 4; i++) osum[c][i] = 0.f;
    const __hip_bfloat16* srcs[3] = {X, Agg, Mn};
    const unsigned short* Wts[3] = {Wt1, Wt2, Wt3};
    const __hip_bfloat16* bs[3] = {b1, b2, b3};
    for (int m = 0; m < 3; m++) {
        __syncthreads();
        const __hip_bfloat16* S = srcs[m];
        for (int idx = threadIdx.x; idx < 64 * 16; idx += 256) {
            int r = idx >> 4, ch = idx & 15;
            uint4 v = make_uint4(0u, 0u, 0u, 0u);
            int n = n0 + r;
            if (n < N) v = ((const uint4*)(S + (size_t)n * D))[ch];
            *(uint4*)&As[r * 136 + ch * 8] = v;
        }
        __syncthreads();
        const unsigned short* arow = &As[(w * 16 + n15) * 136 + quad * 8];
        bf16x8 af[4];
#pragma unroll
        for (int t = 0; t < 4; t++) af[t] = *(const bf16x8*)(arow + t * 32);
        const unsigned short* Wm = Wts[m];
        for (int c = 0; c < 8; c++) {
            f32x4 acc = {0.f, 0.f, 0.f, 0.f};
            const unsigned short* bbase = Wm + (size_t)(c * 16 + n15) * D + quad * 8;
#pragma unroll
            for (int t = 0; t < 4; t++)
                acc = __builtin_amdgcn_mfma_f32_16x16x32_bf16(
                    af[t], *(const bf16x8*)(bbase + t * 32), acc, 0, 0, 0);
            float bb = __bfloat162float(bs[m][c * 16 + n15]);
#pragma unroll
            for (int i = 0; i < 4; i++) osum[c][i] += tanhf(acc[i] + bb);
        }
    }
    int f = flag[0];
    for (int c = 0; c < 8; c++) {
        int col = c * 16 + n15;
#pragma unroll
        for (int i = 0; i < 4; i++) {
            int row = n0 + w * 16 + quad * 4 + i;
            if (row < N) {
                if (f) ((float*)out)[(size_t)row * D + col] = osum[c][i];
                else   ((__hip_bfloat16*)out)[(size_t)row * D + col] =
                           __float2bfloat16(osum[c][i]);
            }
        }
    }
}

// score[e] -> eij[pos[e]] (CSR-sorted position)
__global__ __launch_bounds__(256) void edge_score_kernel(const __hip_bfloat16* __restrict__ Pkey,
                                                         const __hip_bfloat16* __restrict__ Poth,
                                                         const int* __restrict__ keys,
                                                         const int* __restrict__ oths,
                                                         const int* __restrict__ pos,
                                                         const __hip_bfloat16* __restrict__ w,
                                                         const __hip_bfloat16* __restrict__ wb,
                                                         float* __restrict__ eij, int E) {
    int wid = (int)((blockIdx.x * 256 + threadIdx.x) >> 6);
    int lane = threadIdx.x & 63;
    if (wid >= E) return;
    int key = keys[wid], oth = oths[wid];
    const __hip_bfloat162* a = (const __hip_bfloat162*)(Pkey + (size_t)key * D);
    const __hip_bfloat162* b = (const __hip_bfloat162*)(Poth + (size_t)oth * D);
    __hip_bfloat162 av = a[lane], bv = b[lane];
    __hip_bfloat162 wv = ((const __hip_bfloat162*)w)[lane];
    float p = tanhf(__bfloat162float(av.x) + __bfloat162float(bv.x)) * __bfloat162float(wv.x)
            + tanhf(__bfloat162float(av.y) + __bfloat162float(bv.y)) * __bfloat162float(wv.y);
    for (int off = 32; off; off >>= 1) p += __shfl_xor(p, off);
    if (lane == 0) eij[pos[wid]] = p + __bfloat162float(wb[0]);
}

// One wave per node: softmax over contiguous eij segment + 4x-unrolled
// X-row gather aggregation (oth_sorted is contiguous, wave-uniform).
__global__ __launch_bounds__(256) void attn_node_kernel(
    const __hip_bfloat16* __restrict__ X,
    const float* __restrict__ eij_e, const int* __restrict__ ip_e,
    const int* __restrict__ oth_e,
    const float* __restrict__ eij_r, const int* __restrict__ ip_r,
    const int* __restrict__ oth_r,
    __hip_bfloat16* __restrict__ attn_agg, int N) {
    int wid = (int)((blockIdx.x * 256 + threadIdx.x) >> 6);
    int lane = threadIdx.x & 63;
    if (wid >= N) return;
    float accx = 0.f, accy = 0.f;
    for (int side = 0; side < 2; side++) {
        const float* eij = side ? eij_r : eij_e;
        const int* ip  = side ? ip_r  : ip_e;
        const int* oth = side ? oth_r : oth_e;
        int s0 = ip[wid], s1 = ip[wid + 1];
        if (s1 == s0) continue;
        float m = 0.f;  // torch amax include_self over zeros => floor at 0
        for (int i = s0 + lane; i < s1; i += 64) m = fmaxf(m, eij[i]);
        for (int off = 32; off; off >>= 1) m = fmaxf(m, __shfl_xor(m, off));
        float ssum = 0.f;
        for (int i = s0 + lane; i < s1; i += 64) ssum += __expf(eij[i] - m);
        for (int off = 32; off; off >>= 1) ssum += __shfl_xor(ssum, off);
        float inv = 1.f / (ssum + 1e-9f);
        int i = s0;
        for (; i + 4 <= s1; i += 4) {
            int o0 = oth[i], o1 = oth[i + 1], o2 = oth[i + 2], o3 = oth[i + 3];
            float e0 = eij[i], e1 = eij[i + 1], e2 = eij[i + 2], e3 = eij[i + 3];
            __hip_bfloat162 x0 = ((const __hip_bfloat162*)(X + (size_t)o0 * D))[lane];
            __hip_bfloat162 x1 = ((const __hip_bfloat162*)(X + (size_t)o1 * D))[lane];
            __hip_bfloat162 x2 = ((const __hip_bfloat162*)(X + (size_t)o2 * D))[lane];
            __hip_bfloat162 x3 = ((const __hip_bfloat162*)(X + (size_t)o3 * D))[lane];
            float p0 = __expf(e0 - m) * inv, p1 = __expf(e1 - m) * inv;
            float p2 = __expf(e2 - m) * inv, p3 = __expf(e3 - m) * inv;
            accx += p0 * __bfloat162float(x0.x) + p1 * __bfloat162float(x1.x)
                  + p2 * __bfloat162float(x2.x) + p3 * __bfloat162float(x3.x);
            accy += p0 * __bfloat162float(x0.y) + p1 * __bfloat162float(x1.y)
                  + p2 * __bfloat162float(x2.y) + p3 * __bfloat162float(x3.y);
        }
        for (; i < s1; i++) {
            int o = oth[i];
            float p = __expf(eij[i] - m) * inv;
            __hip_bfloat162 xv = ((const __hip_bfloat162*)(X + (size_t)o * D))[lane];
            accx += p * __bfloat162float(xv.x);
            accy += p * __bfloat162float(xv.y);
        }
    }
    __hip_bfloat162 ov;
    ov.x = __float2bfloat16(accx);
    ov.y = __float2bfloat16(accy);
    ((__hip_bfloat162*)(attn_agg + (size_t)wid * D))[lane] = ov;
}

// One wave per node: mean over contiguous dst_sorted segments, unrolled 4x.
__global__ __launch_bounds__(256) void mean_node_kernel(
    const __hip_bfloat16* __restrict__ X,
    const int* __restrict__ ip_ee, const int* __restrict__ dst_ee,
    const int* __restrict__ ip_rr, const int* __restrict__ dst_rr,
    __hip_bfloat16* __restrict__ mean_agg, int N) {
    int wid = (int)((blockIdx.x * 256 + threadIdx.x) >> 6);
    int lane = threadIdx.x & 63;
    if (wid >= N) return;
    float accx = 0.f, accy = 0.f;
    int cnt = 0;
    for (int side = 0; side < 2; side++) {
        const int* ip  = side ? ip_rr  : ip_ee;
        const int* dst = side ? dst_rr : dst_ee;
        int s0 = ip[wid], s1 = ip[wid + 1];
        cnt += s1 - s0;
        int i = s0;
        for (; i + 4 <= s1; i += 4) {
            int o0 = dst[i], o1 = dst[i + 1], o2 = dst[i + 2], o3 = dst[i + 3];
            __hip_bfloat162 x0 = ((const __hip_bfloat162*)(X + (size_t)o0 * D))[lane];
            __hip_bfloat162 x1 = ((const __hip_bfloat162*)(X + (size_t)o1 * D))[lane];
            __hip_bfloat162 x2 = ((const __hip_bfloat162*)(X + (size_t)o2 * D))[lane];
            __hip_bfloat162 x3 = ((const __hip_bfloat162*)(X + (size_t)o3 * D))[lane];
            accx += __bfloat162float(x0.x) + __bfloat162float(x1.x)
                  + __bfloat162float(x2.x) + __bfloat162float(x3.x);
            accy += __bfloat162float(x0.y) + __bfloat162float(x1.y)
                  + __bfloat162float(x2.y) + __bfloat162float(x3.y);
        }
        for (; i < s1; i++) {
            __hip_bfloat162 xv = ((const __hip_bfloat162*)(X + (size_t)dst[i] * D))[lane];
            accx += __bfloat162float(xv.x);
            accy += __bfloat162float(xv.y);
        }
    }
    float inv = 1.f / fmaxf((float)cnt, 1.f);
    __hip_bfloat162 ov;
    ov.x = __float2bfloat16(accx * inv);
    ov.y = __float2bfloat16(accy * inv);
    ((__hip_bfloat162*)(mean_agg + (size_t)wid * D))[lane] = ov;
}

extern "C" void kernel_launch(void* const* d_in, const int* in_sizes, int n_in,
                              void* d_out, int out_size, void* d_ws, size_t ws_size,
                              hipStream_t stream) {
    const int* er_src = (const int*)d_in[15];
    const int* er_dst = (const int*)d_in[16];
    const int* ee_src = (const int*)d_in[17];
    const int* ee_dst = (const int*)d_in[18];
    const int* rr_src = (const int*)d_in[19];
    const int* rr_dst = (const int*)d_in[20];

    int N   = in_sizes[0] / D;
    int Eer = in_sizes[15];
    int Eee = in_sizes[17];
    int Err = in_sizes[19];

    char* ws = (char*)d_ws;
    size_t off = 0;
    auto alloc = [&](size_t bytes) -> void* {
        void* p = ws + off;
        off = (off + bytes + 255) & ~(size_t)255;
        return p;
    };
    int ntpa = (N + TILE - 1) / TILE;
    int T = 4 * ntpa;
    int* flag   = (int*)alloc(256);
    int* pos_e  = (int*)alloc((size_t)Eer * 4);
    int* pos_r  = (int*)alloc((size_t)Eer * 4);
    int* oth_e  = (int*)alloc((size_t)Eer * 4);
    int* oth_r  = (int*)alloc((size_t)Eer * 4);
    int* dst_ee = (int*)alloc((size_t)Eee * 4);
    int* dst_rr = (int*)alloc((size_t)Err * 4);
    int* indptr = (int*)alloc((size_t)4 * (N + 1) * 4);
    int* degcur = (int*)alloc((size_t)4 * N * 4);
    int* tsum   = (int*)alloc((size_t)T * 4);
    int* toff   = (int*)alloc((size_t)T * 4);
    float* eij_e = (float*)alloc((size_t)Eer * 4);
    float* eij_r = (float*)alloc((size_t)Eer * 4);
    __hip_bfloat16* Xc = (__hip_bfloat16*)alloc((size_t)N * D * 2);
    __hip_bfloat16* part0 = (__hip_bfloat16*)alloc((size_t)N * D * 2);
    __hip_bfloat16* part1 = (__hip_bfloat16*)alloc((size_t)N * D * 2);
    __hip_bfloat16* attn_agg = part0;  // parts die after 2nd edge_score
    __hip_bfloat16* mean_agg = part1;
    unsigned short* WtA = (unsigned short*)alloc((size_t)256 * 128 * 2);
    unsigned short* WtR = (unsigned short*)alloc((size_t)256 * 128 * 2);
    unsigned short* Wt1 = (unsigned short*)alloc((size_t)128 * 128 * 2);
    unsigned short* Wt2 = (unsigned short*)alloc((size_t)128 * 128 * 2);
    unsigned short* Wt3 = (unsigned short*)alloc((size_t)128 * 128 * 2);
    ConvBatch cb;
    int widx[14] = {1, 2, 3, 4, 5, 6, 7, 8, 9, 10, 11, 12, 13, 14};
    for (int i = 0; i < 14; i++) {
        cb.src[i] = d_in[widx[i]];
        cb.n[i] = in_sizes[widx[i]];
        cb.dst[i] = (__hip_bfloat16*)alloc((size_t)cb.n[i] * 2);
    }
    const __hip_bfloat16* bae = cb.dst[1];
    const __hip_bfloat16* w0w = cb.dst[2];
    const __hip_bfloat16* w0b = cb.dst[3];
    const __hip_bfloat16* bar_= cb.dst[5];
    const __hip_bfloat16* w1w = cb.dst[6];
    const __hip_bfloat16* w1b = cb.dst[7];
    const __hip_bfloat16* b1  = cb.dst[9];
    const __hip_bfloat16* b2  = cb.dst[11];
    const __hip_bfloat16* b3  = cb.dst[13];
    (void)n_in; (void)out_size;
    if (off > ws_size) return;  // diagnostic: zeros => absmax ~2.58, not NaN

    // ---- dtype detect + canonicalize ----
    detect_kernel<<<1, 256, 0, stream>>>((const unsigned short*)d_in[0], flag);
    conv_weights_kernel<<<14, 256, 0, stream>>>(cb, flag);
    conv_x_kernel<<<(N * D + 255) / 256, 256, 0, stream>>>(d_in[0], Xc, N * D, flag);
    TransBatch tb;
    tb.base[0] = d_in[1];  tb.off[0] = 0;         tb.dst[0] = WtA;
    tb.base[1] = d_in[1];  tb.off[1] = 128 * 128; tb.dst[1] = WtA + 128 * 128;
    tb.base[2] = d_in[5];  tb.off[2] = 0;         tb.dst[2] = WtR;
    tb.base[3] = d_in[5];  tb.off[3] = 128 * 128; tb.dst[3] = WtR + 128 * 128;
    tb.base[4] = d_in[9];  tb.off[4] = 0;         tb.dst[4] = Wt1;
    tb.base[5] = d_in[11]; tb.off[5] = 0;         tb.dst[5] = Wt2;
    tb.base[6] = d_in[13]; tb.off[6] = 0;         tb.dst[6] = Wt3;
    trans_kernel<<<7, 256, 0, stream>>>(tb, flag);

    // ---- CSR build (4 keys: er_src, er_dst, ee_src, rr_src) ----
    zero_kernel<<<(4 * N + 255) / 256, 256, 0, stream>>>(degcur, 4 * N);
    count_kernel<<<(Eer + 255) / 256, 256, 0, stream>>>(er_src, Eer, degcur);
    count_kernel<<<(Eer + 255) / 256, 256, 0, stream>>>(er_dst, Eer, degcur + N);
    count_kernel<<<(Eee + 255) / 256, 256, 0, stream>>>(ee_src, Eee, degcur + 2 * N);
    count_kernel<<<(Err + 255) / 256, 256, 0, stream>>>(rr_src, Err, degcur + 3 * N);
    scan_partial_kernel<<<T, 256, 0, stream>>>(degcur, tsum, N, ntpa);
    scan_tiles_kernel<<<1, 256, 0, stream>>>(tsum, toff, indptr, N, ntpa);
    scan_final_kernel<<<T, 256, 0, stream>>>(degcur, toff, indptr, N, ntpa);
    scatter_attn_kernel<<<(Eer + 255) / 256, 256, 0, stream>>>(er_src, er_dst, Eer,
                                                               degcur, pos_e, oth_e);
    scatter_attn_kernel<<<(Eer + 255) / 256, 256, 0, stream>>>(er_dst, er_src, Eer,
                                                               degcur + N, pos_r, oth_r);
    scatter_mean_kernel<<<(Eee + 255) / 256, 256, 0, stream>>>(ee_src, ee_dst, Eee,
                                                               degcur + 2 * N, dst_ee);
    scatter_mean_kernel<<<(Err + 255) / 256, 256, 0, stream>>>(rr_src, rr_dst, Err,
                                                               degcur + 3 * N, dst_rr);

    int GB = (N + 63) / 64;
    int EW = (Eer + 3) / 4;  // one wave per edge

    // entity side: pair=[r,h]@Wae; key=src(h part,+bae), oth=dst(r part)
    gemm2_mfma_kernel<<<GB, 256, 0, stream>>>(Xc, WtA, bae, part0, part1, N);
    edge_score_kernel<<<EW, 256, 0, stream>>>(part1, part0, er_src, er_dst, pos_e,
                                              w0w, w0b, eij_e, Eer);

    // relation side: pair=[h,r]@War; key=dst(r part,+bar), oth=src(h part)
    gemm2_mfma_kernel<<<GB, 256, 0, stream>>>(Xc, WtR, bar_, part0, part1, N);
    edge_score_kernel<<<EW, 256, 0, stream>>>(part1, part0, er_dst, er_src, pos_r,
                                              w1w, w1b, eij_r, Eer);

    int NW = (N + 3) / 4;  // one wave per node
    attn_node_kernel<<<NW, 256, 0, stream>>>(Xc, eij_e, indptr, oth_e,
                                             eij_r, indptr + (N + 1), oth_r,
                                             attn_agg, N);
    mean_node_kernel<<<NW, 256, 0, stream>>>(Xc, indptr + 2 * (N + 1), dst_ee,
                                             indptr + 3 * (N + 1), dst_rr,
                                             mean_agg, N);
    final_mfma_kernel<<<GB, 256, 0, stream>>>(Xc, attn_agg, mean_agg,
                                              Wt1, b1, Wt2, b2, Wt3, b3,
                                              d_out, flag, N);
}

// Round 7
// 980.141 us; speedup vs baseline: 1.8519x; 1.0281x over previous
//
#include <hip/hip_runtime.h>
#include <hip/hip_bf16.h>

#define D 128
#define TILE 2048

typedef __bf16 bf16x8 __attribute__((ext_vector_type(8)));
typedef float f32x4 __attribute__((ext_vector_type(4)));

// fast tanh: 1 - 2/(e^{2|x|}+1), sign-restored. v_exp + v_rcp, branch-free,
// saturates to +-1 for large |x| (exp->inf => rcp->0). ~1e-6 rel err.
__device__ __forceinline__ float tanh_fast(float x) {
    float e = __expf(2.0f * fabsf(x));
    float t = 1.0f - 2.0f * __builtin_amdgcn_rcpf(e + 1.0f);
    return copysignf(t, x);
}

// ---- dtype detection: are float inputs f32 or bf16 on device? flag=1 => f32.
__global__ __launch_bounds__(256) void detect_kernel(const unsigned short* __restrict__ x,
                                                     int* __restrict__ flag) {
    int t = threadIdx.x;
    int cnt = 0;
    for (int i = t; i < 4096; i += 256) {
        unsigned e = (x[i] >> 7) & 0xFFu;
        if (e == 0xFFu || e >= 0x90u || (e >= 1u && e <= 0x6Eu)) cnt++;
    }
    __shared__ int sh[256];
    sh[t] = cnt;
    __syncthreads();
    for (int off = 128; off; off >>= 1) {
        if (t < off) sh[t] += sh[t + off];
        __syncthreads();
    }
    if (t == 0) flag[0] = (sh[0] > 800) ? 1 : 0;
}

struct ConvBatch {
    const void* src[14];
    __hip_bfloat16* dst[14];
    int n[14];
};

__global__ __launch_bounds__(256) void conv_weights_kernel(ConvBatch cb,
                                                           const int* __restrict__ flag) {
    int a = blockIdx.x;
    const void* s = cb.src[a];
    __hip_bfloat16* d = cb.dst[a];
    int n = cb.n[a];
    int f = flag[0];
    for (int i = threadIdx.x; i < n; i += 256) {
        d[i] = f ? __float2bfloat16(((const float*)s)[i])
                 : ((const __hip_bfloat16*)s)[i];
    }
}

__global__ __launch_bounds__(256) void conv_x_kernel(const void* __restrict__ src,
                                                     __hip_bfloat16* __restrict__ dst,
                                                     int n, const int* __restrict__ flag) {
    int i = blockIdx.x * 256 + threadIdx.x;
    int f = flag[0];
    if (i < n)
        dst[i] = f ? __float2bfloat16(((const float*)src)[i])
                   : ((const __hip_bfloat16*)src)[i];
}

// ---- weight transpose: 7 independent 128x128 blocks -> Wt[c][k] = W[k][c] (bf16)
struct TransBatch {
    const void* base[7];
    int off[7];
    unsigned short* dst[7];
};

__global__ __launch_bounds__(256) void trans_kernel(TransBatch tb,
                                                    const int* __restrict__ flag) {
    int a = blockIdx.x;
    int f = flag[0];
    const float* sf = (const float*)tb.base[a] + tb.off[a];
    const unsigned short* sb = (const unsigned short*)tb.base[a] + tb.off[a];
    unsigned short* d = tb.dst[a];
    for (int idx = threadIdx.x; idx < 128 * 128; idx += 256) {
        int k = idx >> 7, c = idx & 127;
        __hip_bfloat16 v;
        if (f) v = __float2bfloat16(sf[idx]);
        else   v = *(const __hip_bfloat16*)&sb[idx];
        d[c * 128 + k] = *(unsigned short*)&v;
    }
}

__global__ __launch_bounds__(256) void zero_kernel(int* p, int n) {
    int i = blockIdx.x * 256 + threadIdx.x;
    if (i < n) p[i] = 0;
}

__global__ __launch_bounds__(256) void count_kernel(const int* __restrict__ keys, int E,
                                                    int* __restrict__ deg) {
    int i = blockIdx.x * 256 + threadIdx.x;
    if (i < E) atomicAdd(&deg[keys[i]], 1);
}

// ---- hierarchical scan, phase 1: per-tile sums. grid = 4 * ntpa blocks.
__global__ __launch_bounds__(256) void scan_partial_kernel(const int* __restrict__ deg,
                                                           int* __restrict__ tsum,
                                                           int N, int ntpa) {
    int a = blockIdx.x / ntpa, t = blockIdx.x % ntpa;
    const int* d = deg + (size_t)a * N + (size_t)t * TILE;
    int lim = N - t * TILE; if (lim > TILE) lim = TILE;
    int base = threadIdx.x * 8;
    int s = 0;
#pragma unroll
    for (int j = 0; j < 8; j++) {
        int i = base + j;
        if (i < lim) s += d[i];
    }
    __shared__ int sh[256];
    sh[threadIdx.x] = s;
    __syncthreads();
    for (int off = 128; off; off >>= 1) {
        if (threadIdx.x < off) sh[threadIdx.x] += sh[threadIdx.x + off];
        __syncthreads();
    }
    if (threadIdx.x == 0) tsum[blockIdx.x] = sh[0];
}

// ---- phase 2: exclusive scan of tile sums per array (ntpa <= 256); one block.
__global__ __launch_bounds__(256) void scan_tiles_kernel(const int* __restrict__ tsum,
                                                         int* __restrict__ toff,
                                                         int* __restrict__ indptr,
                                                         int N, int ntpa) {
    __shared__ int tmp[256];
    int t = threadIdx.x;
    for (int a = 0; a < 4; a++) {
        int v = (t < ntpa) ? tsum[a * ntpa + t] : 0;
        tmp[t] = v;
        __syncthreads();
        for (int off = 1; off < 256; off <<= 1) {
            int u = (t >= off) ? tmp[t - off] : 0;
            __syncthreads();
            tmp[t] += u;
            __syncthreads();
        }
        if (t < ntpa) toff[a * ntpa + t] = tmp[t] - v;  // exclusive
        if (t == ntpa - 1) indptr[(size_t)a * (N + 1) + N] = tmp[t];
        __syncthreads();
    }
}

// ---- phase 3: intra-tile scan + tile offset; writes indptr and cursor.
__global__ __launch_bounds__(256) void scan_final_kernel(int* __restrict__ degcur,
                                                         const int* __restrict__ toff,
                                                         int* __restrict__ indptr,
                                                         int N, int ntpa) {
    int a = blockIdx.x / ntpa, t = blockIdx.x % ntpa;
    int* d = degcur + (size_t)a * N + (size_t)t * TILE;
    int* ip = indptr + (size_t)a * (N + 1) + (size_t)t * TILE;
    int lim = N - t * TILE; if (lim > TILE) lim = TILE;
    int base = threadIdx.x * 8;
    int v[8];
    int s = 0;
#pragma unroll
    for (int j = 0; j < 8; j++) {
        int i = base + j;
        v[j] = (i < lim) ? d[i] : 0;
        s += v[j];
    }
    __shared__ int tmp[256];
    tmp[threadIdx.x] = s;
    __syncthreads();
    for (int off = 1; off < 256; off <<= 1) {
        int u = (threadIdx.x >= off) ? tmp[threadIdx.x - off] : 0;
        __syncthreads();
        tmp[threadIdx.x] += u;
        __syncthreads();
    }
    int run = toff[blockIdx.x] + tmp[threadIdx.x] - s;
#pragma unroll
    for (int j = 0; j < 8; j++) {
        int i = base + j;
        if (i < lim) { ip[i] = run; d[i] = run; run += v[j]; }
    }
}

// attention sides: record CSR slot pos[e] and scatter the gather-index directly.
__global__ __launch_bounds__(256) void scatter_attn_kernel(const int* __restrict__ keys,
                                                           const int* __restrict__ oths, int E,
                                                           int* __restrict__ cursor,
                                                           int* __restrict__ pos,
                                                           int* __restrict__ oth_sorted) {
    int i = blockIdx.x * 256 + threadIdx.x;
    if (i < E) {
        int p = atomicAdd(&cursor[keys[i]], 1);
        pos[i] = p;
        oth_sorted[p] = oths[i];
    }
}

// mean sides: only the sorted gather-index is needed.
__global__ __launch_bounds__(256) void scatter_mean_kernel(const int* __restrict__ keys,
                                                           const int* __restrict__ dsts, int E,
                                                           int* __restrict__ cursor,
                                                           int* __restrict__ dst_sorted) {
    int i = blockIdx.x * 256 + threadIdx.x;
    if (i < E) {
        int p = atomicAdd(&cursor[keys[i]], 1);
        dst_sorted[p] = dsts[i];
    }
}

// ---- MFMA GEMM: parts[n] = X[n] @ {Wt rows 0..127 | 128..255}^T (+bias on part1)
__global__ __launch_bounds__(256) void gemm2_mfma_kernel(
    const __hip_bfloat16* __restrict__ X,
    const unsigned short* __restrict__ Wt,      // 256 x 128, Wt[c][k]
    const __hip_bfloat16* __restrict__ bias,    // 128 (part1 only)
    __hip_bfloat16* __restrict__ part0,
    __hip_bfloat16* __restrict__ part1, int N) {
    __shared__ __align__(16) unsigned short As[64 * 136];
    int n0 = blockIdx.x * 64;
    for (int idx = threadIdx.x; idx < 64 * 16; idx += 256) {
        int r = idx >> 4, ch = idx & 15;
        uint4 v = make_uint4(0u, 0u, 0u, 0u);
        int n = n0 + r;
        if (n < N) v = ((const uint4*)(X + (size_t)n * D))[ch];
        *(uint4*)&As[r * 136 + ch * 8] = v;
    }
    __syncthreads();
    int w = threadIdx.x >> 6, lane = threadIdx.x & 63;
    int n15 = lane & 15, quad = lane >> 4;
    const unsigned short* arow = &As[(w * 16 + n15) * 136 + quad * 8];
    bf16x8 af[4];
#pragma unroll
    for (int t = 0; t < 4; t++) af[t] = *(const bf16x8*)(arow + t * 32);
    for (int c = 0; c < 16; c++) {
        f32x4 acc = {0.f, 0.f, 0.f, 0.f};
        const unsigned short* bbase = Wt + (size_t)(c * 16 + n15) * D + quad * 8;
#pragma unroll
        for (int t = 0; t < 4; t++)
            acc = __builtin_amdgcn_mfma_f32_16x16x32_bf16(
                af[t], *(const bf16x8*)(bbase + t * 32), acc, 0, 0, 0);
        float b;
        __hip_bfloat16* outp;
        int col;
        if (c < 8) { outp = part0; col = c * 16 + n15; b = 0.f; }
        else       { outp = part1; col = c * 16 + n15 - 128;
                     b = __bfloat162float(bias[col]); }
#pragma unroll
        for (int i = 0; i < 4; i++) {
            int row = n0 + w * 16 + quad * 4 + i;
            if (row < N) outp[(size_t)row * D + col] = __float2bfloat16(acc[i] + b);
        }
    }
}

// ---- MFMA final: out = tanh(X@W1+b1)+tanh(A@W2+b2)+tanh(M@W3+b3)
__global__ __launch_bounds__(256) void final_mfma_kernel(
    const __hip_bfloat16* __restrict__ X, const __hip_bfloat16* __restrict__ Agg,
    const __hip_bfloat16* __restrict__ Mn,
    const unsigned short* __restrict__ Wt1, const __hip_bfloat16* __restrict__ b1,
    const unsigned short* __restrict__ Wt2, const __hip_bfloat16* __restrict__ b2,
    const unsigned short* __restrict__ Wt3, const __hip_bfloat16* __restrict__ b3,
    void* __restrict__ out, const int* __restrict__ flag, int N) {
    __shared__ __align__(16) unsigned short As[64 * 136];
    int n0 = blockIdx.x * 64;
    int w = threadIdx.x >> 6, lane = threadIdx.x & 63;
    int n15 = lane & 15, quad = lane >> 4;
    float osum[8][4];
#pragma unroll
    for (int c = 0; c < 8; c++)
#pragma unroll
        for (int i = 0; i < 4; i++) osum[c][i] = 0.f;
    const __hip_bfloat16* srcs[3] = {X, Agg, Mn};
    const unsigned short* Wts[3] = {Wt1, Wt2, Wt3};
    const __hip_bfloat16* bs[3] = {b1, b2, b3};
    for (int m = 0; m < 3; m++) {
        __syncthreads();
        const __hip_bfloat16* S = srcs[m];
        for (int idx = threadIdx.x; idx < 64 * 16; idx += 256) {
            int r = idx >> 4, ch = idx & 15;
            uint4 v = make_uint4(0u, 0u, 0u, 0u);
            int n = n0 + r;
            if (n < N) v = ((const uint4*)(S + (size_t)n * D))[ch];
            *(uint4*)&As[r * 136 + ch * 8] = v;
        }
        __syncthreads();
        const unsigned short* arow = &As[(w * 16 + n15) * 136 + quad * 8];
        bf16x8 af[4];
#pragma unroll
        for (int t = 0; t < 4; t++) af[t] = *(const bf16x8*)(arow + t * 32);
        const unsigned short* Wm = Wts[m];
        for (int c = 0; c < 8; c++) {
            f32x4 acc = {0.f, 0.f, 0.f, 0.f};
            const unsigned short* bbase = Wm + (size_t)(c * 16 + n15) * D + quad * 8;
#pragma unroll
            for (int t = 0; t < 4; t++)
                acc = __builtin_amdgcn_mfma_f32_16x16x32_bf16(
                    af[t], *(const bf16x8*)(bbase + t * 32), acc, 0, 0, 0);
            float bb = __bfloat162float(bs[m][c * 16 + n15]);
#pragma unroll
            for (int i = 0; i < 4; i++) osum[c][i] += tanh_fast(acc[i] + bb);
        }
    }
    int f = flag[0];
    for (int c = 0; c < 8; c++) {
        int col = c * 16 + n15;
#pragma unroll
        for (int i = 0; i < 4; i++) {
            int row = n0 + w * 16 + quad * 4 + i;
            if (row < N) {
                if (f) ((float*)out)[(size_t)row * D + col] = osum[c][i];
                else   ((__hip_bfloat16*)out)[(size_t)row * D + col] =
                           __float2bfloat16(osum[c][i]);
            }
        }
    }
}

// score[e] -> eij[pos[e]] (CSR-sorted position)
__global__ __launch_bounds__(256) void edge_score_kernel(const __hip_bfloat16* __restrict__ Pkey,
                                                         const __hip_bfloat16* __restrict__ Poth,
                                                         const int* __restrict__ keys,
                                                         const int* __restrict__ oths,
                                                         const int* __restrict__ pos,
                                                         const __hip_bfloat16* __restrict__ w,
                                                         const __hip_bfloat16* __restrict__ wb,
                                                         float* __restrict__ eij, int E) {
    int wid = (int)((blockIdx.x * 256 + threadIdx.x) >> 6);
    int lane = threadIdx.x & 63;
    if (wid >= E) return;
    int key = keys[wid], oth = oths[wid];
    const __hip_bfloat162* a = (const __hip_bfloat162*)(Pkey + (size_t)key * D);
    const __hip_bfloat162* b = (const __hip_bfloat162*)(Poth + (size_t)oth * D);
    __hip_bfloat162 av = a[lane], bv = b[lane];
    __hip_bfloat162 wv = ((const __hip_bfloat162*)w)[lane];
    float p = tanh_fast(__bfloat162float(av.x) + __bfloat162float(bv.x)) * __bfloat162float(wv.x)
            + tanh_fast(__bfloat162float(av.y) + __bfloat162float(bv.y)) * __bfloat162float(wv.y);
    for (int off = 32; off; off >>= 1) p += __shfl_xor(p, off);
    if (lane == 0) eij[pos[wid]] = p + __bfloat162float(wb[0]);
}

// One wave per node: softmax over contiguous eij segment + 4x-unrolled
// X-row gather aggregation (oth_sorted is contiguous, wave-uniform).
__global__ __launch_bounds__(256) void attn_node_kernel(
    const __hip_bfloat16* __restrict__ X,
    const float* __restrict__ eij_e, const int* __restrict__ ip_e,
    const int* __restrict__ oth_e,
    const float* __restrict__ eij_r, const int* __restrict__ ip_r,
    const int* __restrict__ oth_r,
    __hip_bfloat16* __restrict__ attn_agg, int N) {
    int wid = (int)((blockIdx.x * 256 + threadIdx.x) >> 6);
    int lane = threadIdx.x & 63;
    if (wid >= N) return;
    float accx = 0.f, accy = 0.f;
    for (int side = 0; side < 2; side++) {
        const float* eij = side ? eij_r : eij_e;
        const int* ip  = side ? ip_r  : ip_e;
        const int* oth = side ? oth_r : oth_e;
        int s0 = ip[wid], s1 = ip[wid + 1];
        if (s1 == s0) continue;
        float m = 0.f;  // torch amax include_self over zeros => floor at 0
        for (int i = s0 + lane; i < s1; i += 64) m = fmaxf(m, eij[i]);
        for (int off = 32; off; off >>= 1) m = fmaxf(m, __shfl_xor(m, off));
        float ssum = 0.f;
        for (int i = s0 + lane; i < s1; i += 64) ssum += __expf(eij[i] - m);
        for (int off = 32; off; off >>= 1) ssum += __shfl_xor(ssum, off);
        float inv = 1.f / (ssum + 1e-9f);
        int i = s0;
        for (; i + 4 <= s1; i += 4) {
            int o0 = oth[i], o1 = oth[i + 1], o2 = oth[i + 2], o3 = oth[i + 3];
            float e0 = eij[i], e1 = eij[i + 1], e2 = eij[i + 2], e3 = eij[i + 3];
            __hip_bfloat162 x0 = ((const __hip_bfloat162*)(X + (size_t)o0 * D))[lane];
            __hip_bfloat162 x1 = ((const __hip_bfloat162*)(X + (size_t)o1 * D))[lane];
            __hip_bfloat162 x2 = ((const __hip_bfloat162*)(X + (size_t)o2 * D))[lane];
            __hip_bfloat162 x3 = ((const __hip_bfloat162*)(X + (size_t)o3 * D))[lane];
            float p0 = __expf(e0 - m) * inv, p1 = __expf(e1 - m) * inv;
            float p2 = __expf(e2 - m) * inv, p3 = __expf(e3 - m) * inv;
            accx += p0 * __bfloat162float(x0.x) + p1 * __bfloat162float(x1.x)
                  + p2 * __bfloat162float(x2.x) + p3 * __bfloat162float(x3.x);
            accy += p0 * __bfloat162float(x0.y) + p1 * __bfloat162float(x1.y)
                  + p2 * __bfloat162float(x2.y) + p3 * __bfloat162float(x3.y);
        }
        for (; i < s1; i++) {
            int o = oth[i];
            float p = __expf(eij[i] - m) * inv;
            __hip_bfloat162 xv = ((const __hip_bfloat162*)(X + (size_t)o * D))[lane];
            accx += p * __bfloat162float(xv.x);
            accy += p * __bfloat162float(xv.y);
        }
    }
    __hip_bfloat162 ov;
    ov.x = __float2bfloat16(accx);
    ov.y = __float2bfloat16(accy);
    ((__hip_bfloat162*)(attn_agg + (size_t)wid * D))[lane] = ov;
}

// One wave per node: mean over contiguous dst_sorted segments, unrolled 4x.
__global__ __launch_bounds__(256) void mean_node_kernel(
    const __hip_bfloat16* __restrict__ X,
    const int* __restrict__ ip_ee, const int* __restrict__ dst_ee,
    const int* __restrict__ ip_rr, const int* __restrict__ dst_rr,
    __hip_bfloat16* __restrict__ mean_agg, int N) {
    int wid = (int)((blockIdx.x * 256 + threadIdx.x) >> 6);
    int lane = threadIdx.x & 63;
    if (wid >= N) return;
    float accx = 0.f, accy = 0.f;
    int cnt = 0;
    for (int side = 0; side < 2; side++) {
        const int* ip  = side ? ip_rr  : ip_ee;
        const int* dst = side ? dst_rr : dst_ee;
        int s0 = ip[wid], s1 = ip[wid + 1];
        cnt += s1 - s0;
        int i = s0;
        for (; i + 4 <= s1; i += 4) {
            int o0 = dst[i], o1 = dst[i + 1], o2 = dst[i + 2], o3 = dst[i + 3];
            __hip_bfloat162 x0 = ((const __hip_bfloat162*)(X + (size_t)o0 * D))[lane];
            __hip_bfloat162 x1 = ((const __hip_bfloat162*)(X + (size_t)o1 * D))[lane];
            __hip_bfloat162 x2 = ((const __hip_bfloat162*)(X + (size_t)o2 * D))[lane];
            __hip_bfloat162 x3 = ((const __hip_bfloat162*)(X + (size_t)o3 * D))[lane];
            accx += __bfloat162float(x0.x) + __bfloat162float(x1.x)
                  + __bfloat162float(x2.x) + __bfloat162float(x3.x);
            accy += __bfloat162float(x0.y) + __bfloat162float(x1.y)
                  + __bfloat162float(x2.y) + __bfloat162float(x3.y);
        }
        for (; i < s1; i++) {
            __hip_bfloat162 xv = ((const __hip_bfloat162*)(X + (size_t)dst[i] * D))[lane];
            accx += __bfloat162float(xv.x);
            accy += __bfloat162float(xv.y);
        }
    }
    float inv = 1.f / fmaxf((float)cnt, 1.f);
    __hip_bfloat162 ov;
    ov.x = __float2bfloat16(accx * inv);
    ov.y = __float2bfloat16(accy * inv);
    ((__hip_bfloat162*)(mean_agg + (size_t)wid * D))[lane] = ov;
}

extern "C" void kernel_launch(void* const* d_in, const int* in_sizes, int n_in,
                              void* d_out, int out_size, void* d_ws, size_t ws_size,
                              hipStream_t stream) {
    const int* er_src = (const int*)d_in[15];
    const int* er_dst = (const int*)d_in[16];
    const int* ee_src = (const int*)d_in[17];
    const int* ee_dst = (const int*)d_in[18];
    const int* rr_src = (const int*)d_in[19];
    const int* rr_dst = (const int*)d_in[20];

    int N   = in_sizes[0] / D;
    int Eer = in_sizes[15];
    int Eee = in_sizes[17];
    int Err = in_sizes[19];

    char* ws = (char*)d_ws;
    size_t off = 0;
    auto alloc = [&](size_t bytes) -> void* {
        void* p = ws + off;
        off = (off + bytes + 255) & ~(size_t)255;
        return p;
    };
    int ntpa = (N + TILE - 1) / TILE;
    int T = 4 * ntpa;
    int* flag   = (int*)alloc(256);
    int* pos_e  = (int*)alloc((size_t)Eer * 4);
    int* pos_r  = (int*)alloc((size_t)Eer * 4);
    int* oth_e  = (int*)alloc((size_t)Eer * 4);
    int* oth_r  = (int*)alloc((size_t)Eer * 4);
    int* dst_ee = (int*)alloc((size_t)Eee * 4);
    int* dst_rr = (int*)alloc((size_t)Err * 4);
    int* indptr = (int*)alloc((size_t)4 * (N + 1) * 4);
    int* degcur = (int*)alloc((size_t)4 * N * 4);
    int* tsum   = (int*)alloc((size_t)T * 4);
    int* toff   = (int*)alloc((size_t)T * 4);
    float* eij_e = (float*)alloc((size_t)Eer * 4);
    float* eij_r = (float*)alloc((size_t)Eer * 4);
    __hip_bfloat16* Xc = (__hip_bfloat16*)alloc((size_t)N * D * 2);
    __hip_bfloat16* part0 = (__hip_bfloat16*)alloc((size_t)N * D * 2);
    __hip_bfloat16* part1 = (__hip_bfloat16*)alloc((size_t)N * D * 2);
    __hip_bfloat16* attn_agg = part0;  // parts die after 2nd edge_score
    __hip_bfloat16* mean_agg = part1;
    unsigned short* WtA = (unsigned short*)alloc((size_t)256 * 128 * 2);
    unsigned short* WtR = (unsigned short*)alloc((size_t)256 * 128 * 2);
    unsigned short* Wt1 = (unsigned short*)alloc((size_t)128 * 128 * 2);
    unsigned short* Wt2 = (unsigned short*)alloc((size_t)128 * 128 * 2);
    unsigned short* Wt3 = (unsigned short*)alloc((size_t)128 * 128 * 2);
    ConvBatch cb;
    int widx[14] = {1, 2, 3, 4, 5, 6, 7, 8, 9, 10, 11, 12, 13, 14};
    for (int i = 0; i < 14; i++) {
        cb.src[i] = d_in[widx[i]];
        cb.n[i] = in_sizes[widx[i]];
        cb.dst[i] = (__hip_bfloat16*)alloc((size_t)cb.n[i] * 2);
    }
    const __hip_bfloat16* bae = cb.dst[1];
    const __hip_bfloat16* w0w = cb.dst[2];
    const __hip_bfloat16* w0b = cb.dst[3];
    const __hip_bfloat16* bar_= cb.dst[5];
    const __hip_bfloat16* w1w = cb.dst[6];
    const __hip_bfloat16* w1b = cb.dst[7];
    const __hip_bfloat16* b1  = cb.dst[9];
    const __hip_bfloat16* b2  = cb.dst[11];
    const __hip_bfloat16* b3  = cb.dst[13];
    (void)n_in; (void)out_size;
    if (off > ws_size) return;  // diagnostic: zeros => absmax ~2.58, not NaN

    // ---- dtype detect + canonicalize ----
    detect_kernel<<<1, 256, 0, stream>>>((const unsigned short*)d_in[0], flag);
    conv_weights_kernel<<<14, 256, 0, stream>>>(cb, flag);
    conv_x_kernel<<<(N * D + 255) / 256, 256, 0, stream>>>(d_in[0], Xc, N * D, flag);
    TransBatch tb;
    tb.base[0] = d_in[1];  tb.off[0] = 0;         tb.dst[0] = WtA;
    tb.base[1] = d_in[1];  tb.off[1] = 128 * 128; tb.dst[1] = WtA + 128 * 128;
    tb.base[2] = d_in[5];  tb.off[2] = 0;         tb.dst[2] = WtR;
    tb.base[3] = d_in[5];  tb.off[3] = 128 * 128; tb.dst[3] = WtR + 128 * 128;
    tb.base[4] = d_in[9];  tb.off[4] = 0;         tb.dst[4] = Wt1;
    tb.base[5] = d_in[11]; tb.off[5] = 0;         tb.dst[5] = Wt2;
    tb.base[6] = d_in[13]; tb.off[6] = 0;         tb.dst[6] = Wt3;
    trans_kernel<<<7, 256, 0, stream>>>(tb, flag);

    // ---- CSR build (4 keys: er_src, er_dst, ee_src, rr_src) ----
    zero_kernel<<<(4 * N + 255) / 256, 256, 0, stream>>>(degcur, 4 * N);
    count_kernel<<<(Eer + 255) / 256, 256, 0, stream>>>(er_src, Eer, degcur);
    count_kernel<<<(Eer + 255) / 256, 256, 0, stream>>>(er_dst, Eer, degcur + N);
    count_kernel<<<(Eee + 255) / 256, 256, 0, stream>>>(ee_src, Eee, degcur + 2 * N);
    count_kernel<<<(Err + 255) / 256, 256, 0, stream>>>(rr_src, Err, degcur + 3 * N);
    scan_partial_kernel<<<T, 256, 0, stream>>>(degcur, tsum, N, ntpa);
    scan_tiles_kernel<<<1, 256, 0, stream>>>(tsum, toff, indptr, N, ntpa);
    scan_final_kernel<<<T, 256, 0, stream>>>(degcur, toff, indptr, N, ntpa);
    scatter_attn_kernel<<<(Eer + 255) / 256, 256, 0, stream>>>(er_src, er_dst, Eer,
                                                               degcur, pos_e, oth_e);
    scatter_attn_kernel<<<(Eer + 255) / 256, 256, 0, stream>>>(er_dst, er_src, Eer,
                                                               degcur + N, pos_r, oth_r);
    scatter_mean_kernel<<<(Eee + 255) / 256, 256, 0, stream>>>(ee_src, ee_dst, Eee,
                                                               degcur + 2 * N, dst_ee);
    scatter_mean_kernel<<<(Err + 255) / 256, 256, 0, stream>>>(rr_src, rr_dst, Err,
                                                               degcur + 3 * N, dst_rr);

    int GB = (N + 63) / 64;
    int EW = (Eer + 3) / 4;  // one wave per edge

    // entity side: pair=[r,h]@Wae; key=src(h part,+bae), oth=dst(r part)
    gemm2_mfma_kernel<<<GB, 256, 0, stream>>>(Xc, WtA, bae, part0, part1, N);
    edge_score_kernel<<<EW, 256, 0, stream>>>(part1, part0, er_src, er_dst, pos_e,
                                              w0w, w0b, eij_e, Eer);

    // relation side: pair=[h,r]@War; key=dst(r part,+bar), oth=src(h part)
    gemm2_mfma_kernel<<<GB, 256, 0, stream>>>(Xc, WtR, bar_, part0, part1, N);
    edge_score_kernel<<<EW, 256, 0, stream>>>(part1, part0, er_dst, er_src, pos_r,
                                              w1w, w1b, eij_r, Eer);

    int NW = (N + 3) / 4;  // one wave per node
    attn_node_kernel<<<NW, 256, 0, stream>>>(Xc, eij_e, indptr, oth_e,
                                             eij_r, indptr + (N + 1), oth_r,
                                             attn_agg, N);
    mean_node_kernel<<<NW, 256, 0, stream>>>(Xc, indptr + 2 * (N + 1), dst_ee,
                                             indptr + 3 * (N + 1), dst_rr,
                                             mean_agg, N);
    final_mfma_kernel<<<GB, 256, 0, stream>>>(Xc, attn_agg, mean_agg,
                                              Wt1, b1, Wt2, b2, Wt3, b3,
                                              d_out, flag, N);
}

// Round 8
// 865.781 us; speedup vs baseline: 2.0965x; 1.1321x over previous
//
#include <hip/hip_runtime.h>
#include <hip/hip_bf16.h>

#define D 128
#define TILE 2048

typedef __bf16 bf16x8 __attribute__((ext_vector_type(8)));
typedef float f32x4 __attribute__((ext_vector_type(4)));

// fast tanh: 1 - 2/(e^{2|x|}+1), sign-restored. v_exp + v_rcp, branch-free,
// saturates to +-1 for large |x|. ~1e-6 rel err.
__device__ __forceinline__ float tanh_fast(float x) {
    float e = __expf(2.0f * fabsf(x));
    float t = 1.0f - 2.0f * __builtin_amdgcn_rcpf(e + 1.0f);
    return copysignf(t, x);
}

// ---- dtype detection: are float inputs f32 or bf16 on device? flag=1 => f32.
__global__ __launch_bounds__(256) void detect_kernel(const unsigned short* __restrict__ x,
                                                     int* __restrict__ flag) {
    int t = threadIdx.x;
    int cnt = 0;
    for (int i = t; i < 4096; i += 256) {
        unsigned e = (x[i] >> 7) & 0xFFu;
        if (e == 0xFFu || e >= 0x90u || (e >= 1u && e <= 0x6Eu)) cnt++;
    }
    __shared__ int sh[256];
    sh[t] = cnt;
    __syncthreads();
    for (int off = 128; off; off >>= 1) {
        if (t < off) sh[t] += sh[t + off];
        __syncthreads();
    }
    if (t == 0) flag[0] = (sh[0] > 800) ? 1 : 0;
}

struct ConvBatch {
    const void* src[14];
    __hip_bfloat16* dst[14];
    int n[14];
};

__global__ __launch_bounds__(256) void conv_weights_kernel(ConvBatch cb,
                                                           const int* __restrict__ flag) {
    int a = blockIdx.x;
    const void* s = cb.src[a];
    __hip_bfloat16* d = cb.dst[a];
    int n = cb.n[a];
    int f = flag[0];
    for (int i = threadIdx.x; i < n; i += 256) {
        d[i] = f ? __float2bfloat16(((const float*)s)[i])
                 : ((const __hip_bfloat16*)s)[i];
    }
}

__global__ __launch_bounds__(256) void conv_x_kernel(const void* __restrict__ src,
                                                     __hip_bfloat16* __restrict__ dst,
                                                     int n, const int* __restrict__ flag) {
    int i = blockIdx.x * 256 + threadIdx.x;
    int f = flag[0];
    if (i < n)
        dst[i] = f ? __float2bfloat16(((const float*)src)[i])
                   : ((const __hip_bfloat16*)src)[i];
}

// ---- weight transpose: 7 independent 128x128 blocks -> Wt[c][k] = W[k][c] (bf16)
struct TransBatch {
    const void* base[7];
    int off[7];
    unsigned short* dst[7];
};

__global__ __launch_bounds__(256) void trans_kernel(TransBatch tb,
                                                    const int* __restrict__ flag) {
    int a = blockIdx.x;
    int f = flag[0];
    const float* sf = (const float*)tb.base[a] + tb.off[a];
    const unsigned short* sb = (const unsigned short*)tb.base[a] + tb.off[a];
    unsigned short* d = tb.dst[a];
    for (int idx = threadIdx.x; idx < 128 * 128; idx += 256) {
        int k = idx >> 7, c = idx & 127;
        __hip_bfloat16 v;
        if (f) v = __float2bfloat16(sf[idx]);
        else   v = *(const __hip_bfloat16*)&sb[idx];
        d[c * 128 + k] = *(unsigned short*)&v;
    }
}

__global__ __launch_bounds__(256) void zero_kernel(int* p, int n) {
    int i = blockIdx.x * 256 + threadIdx.x;
    if (i < n) p[i] = 0;
}

__global__ __launch_bounds__(256) void count_kernel(const int* __restrict__ keys, int E,
                                                    int* __restrict__ deg) {
    int i = blockIdx.x * 256 + threadIdx.x;
    if (i < E) atomicAdd(&deg[keys[i]], 1);
}

// ---- hierarchical scan, phase 1: per-tile sums. grid = 4 * ntpa blocks.
__global__ __launch_bounds__(256) void scan_partial_kernel(const int* __restrict__ deg,
                                                           int* __restrict__ tsum,
                                                           int N, int ntpa) {
    int a = blockIdx.x / ntpa, t = blockIdx.x % ntpa;
    const int* d = deg + (size_t)a * N + (size_t)t * TILE;
    int lim = N - t * TILE; if (lim > TILE) lim = TILE;
    int base = threadIdx.x * 8;
    int s = 0;
#pragma unroll
    for (int j = 0; j < 8; j++) {
        int i = base + j;
        if (i < lim) s += d[i];
    }
    __shared__ int sh[256];
    sh[threadIdx.x] = s;
    __syncthreads();
    for (int off = 128; off; off >>= 1) {
        if (threadIdx.x < off) sh[threadIdx.x] += sh[threadIdx.x + off];
        __syncthreads();
    }
    if (threadIdx.x == 0) tsum[blockIdx.x] = sh[0];
}

// ---- phase 2: exclusive scan of tile sums per array (ntpa <= 256); one block.
__global__ __launch_bounds__(256) void scan_tiles_kernel(const int* __restrict__ tsum,
                                                         int* __restrict__ toff,
                                                         int* __restrict__ indptr,
                                                         int N, int ntpa) {
    __shared__ int tmp[256];
    int t = threadIdx.x;
    for (int a = 0; a < 4; a++) {
        int v = (t < ntpa) ? tsum[a * ntpa + t] : 0;
        tmp[t] = v;
        __syncthreads();
        for (int off = 1; off < 256; off <<= 1) {
            int u = (t >= off) ? tmp[t - off] : 0;
            __syncthreads();
            tmp[t] += u;
            __syncthreads();
        }
        if (t < ntpa) toff[a * ntpa + t] = tmp[t] - v;  // exclusive
        if (t == ntpa - 1) indptr[(size_t)a * (N + 1) + N] = tmp[t];
        __syncthreads();
    }
}

// ---- phase 3: intra-tile scan + tile offset; writes indptr and cursor.
__global__ __launch_bounds__(256) void scan_final_kernel(int* __restrict__ degcur,
                                                         const int* __restrict__ toff,
                                                         int* __restrict__ indptr,
                                                         int N, int ntpa) {
    int a = blockIdx.x / ntpa, t = blockIdx.x % ntpa;
    int* d = degcur + (size_t)a * N + (size_t)t * TILE;
    int* ip = indptr + (size_t)a * (N + 1) + (size_t)t * TILE;
    int lim = N - t * TILE; if (lim > TILE) lim = TILE;
    int base = threadIdx.x * 8;
    int v[8];
    int s = 0;
#pragma unroll
    for (int j = 0; j < 8; j++) {
        int i = base + j;
        v[j] = (i < lim) ? d[i] : 0;
        s += v[j];
    }
    __shared__ int tmp[256];
    tmp[threadIdx.x] = s;
    __syncthreads();
    for (int off = 1; off < 256; off <<= 1) {
        int u = (threadIdx.x >= off) ? tmp[threadIdx.x - off] : 0;
        __syncthreads();
        tmp[threadIdx.x] += u;
        __syncthreads();
    }
    int run = toff[blockIdx.x] + tmp[threadIdx.x] - s;
#pragma unroll
    for (int j = 0; j < 8; j++) {
        int i = base + j;
        if (i < lim) { ip[i] = run; d[i] = run; run += v[j]; }
    }
}

// attention sides: record CSR slot pos[e] and scatter the gather-index directly.
__global__ __launch_bounds__(256) void scatter_attn_kernel(const int* __restrict__ keys,
                                                           const int* __restrict__ oths, int E,
                                                           int* __restrict__ cursor,
                                                           int* __restrict__ pos,
                                                           int* __restrict__ oth_sorted) {
    int i = blockIdx.x * 256 + threadIdx.x;
    if (i < E) {
        int p = atomicAdd(&cursor[keys[i]], 1);
        pos[i] = p;
        oth_sorted[p] = oths[i];
    }
}

// mean sides: only the sorted gather-index is needed.
__global__ __launch_bounds__(256) void scatter_mean_kernel(const int* __restrict__ keys,
                                                           const int* __restrict__ dsts, int E,
                                                           int* __restrict__ cursor,
                                                           int* __restrict__ dst_sorted) {
    int i = blockIdx.x * 256 + threadIdx.x;
    if (i < E) {
        int p = atomicAdd(&cursor[keys[i]], 1);
        dst_sorted[p] = dsts[i];
    }
}

// ---- MFMA GEMM, B staged in LDS per 128-col half.
// parts[n] = X[n] @ {Wt rows 0..127 | 128..255}^T (+bias on part1)
__global__ __launch_bounds__(256) void gemm2_mfma_kernel(
    const __hip_bfloat16* __restrict__ X,
    const unsigned short* __restrict__ Wt,      // 256 x 128, Wt[c][k]
    const __hip_bfloat16* __restrict__ bias,    // 128 (part1 only)
    __hip_bfloat16* __restrict__ part0,
    __hip_bfloat16* __restrict__ part1, int N) {
    __shared__ __align__(16) unsigned short As[64 * 136];
    __shared__ __align__(16) unsigned short Bs[128 * 136];
    int n0 = blockIdx.x * 64;
    for (int idx = threadIdx.x; idx < 64 * 16; idx += 256) {
        int r = idx >> 4, ch = idx & 15;
        uint4 v = make_uint4(0u, 0u, 0u, 0u);
        int n = n0 + r;
        if (n < N) v = ((const uint4*)(X + (size_t)n * D))[ch];
        *(uint4*)&As[r * 136 + ch * 8] = v;
    }
    int w = threadIdx.x >> 6, lane = threadIdx.x & 63;
    int n15 = lane & 15, quad = lane >> 4;
    bf16x8 af[4];
    for (int half = 0; half < 2; half++) {
        for (int idx = threadIdx.x; idx < 128 * 16; idx += 256) {
            int r = idx >> 4, ch = idx & 15;
            uint4 v = ((const uint4*)(Wt + (size_t)(half * 128 + r) * D))[ch];
            *(uint4*)&Bs[r * 136 + ch * 8] = v;
        }
        __syncthreads();
        if (half == 0) {
            const unsigned short* arow = &As[(w * 16 + n15) * 136 + quad * 8];
#pragma unroll
            for (int t = 0; t < 4; t++) af[t] = *(const bf16x8*)(arow + t * 32);
        }
        __hip_bfloat16* outp = half ? part1 : part0;
        for (int c = 0; c < 8; c++) {
            f32x4 acc = {0.f, 0.f, 0.f, 0.f};
            const unsigned short* brow = &Bs[(c * 16 + n15) * 136 + quad * 8];
#pragma unroll
            for (int t = 0; t < 4; t++)
                acc = __builtin_amdgcn_mfma_f32_16x16x32_bf16(
                    af[t], *(const bf16x8*)(brow + t * 32), acc, 0, 0, 0);
            int col = c * 16 + n15;
            float b = half ? __bfloat162float(bias[col]) : 0.f;
#pragma unroll
            for (int i = 0; i < 4; i++) {
                int row = n0 + w * 16 + quad * 4 + i;
                if (row < N) outp[(size_t)row * D + col] = __float2bfloat16(acc[i] + b);
            }
        }
        if (half == 0) __syncthreads();  // all reads of Bs done before restage
    }
}

// ---- MFMA final, B staged in LDS per matrix: out = sum_m tanh(S_m@W_m+b_m)
__global__ __launch_bounds__(256) void final_mfma_kernel(
    const __hip_bfloat16* __restrict__ X, const __hip_bfloat16* __restrict__ Agg,
    const __hip_bfloat16* __restrict__ Mn,
    const unsigned short* __restrict__ Wt1, const __hip_bfloat16* __restrict__ b1,
    const unsigned short* __restrict__ Wt2, const __hip_bfloat16* __restrict__ b2,
    const unsigned short* __restrict__ Wt3, const __hip_bfloat16* __restrict__ b3,
    void* __restrict__ out, const int* __restrict__ flag, int N) {
    __shared__ __align__(16) unsigned short As[64 * 136];
    __shared__ __align__(16) unsigned short Bs[128 * 136];
    int n0 = blockIdx.x * 64;
    int w = threadIdx.x >> 6, lane = threadIdx.x & 63;
    int n15 = lane & 15, quad = lane >> 4;
    float osum[8][4];
#pragma unroll
    for (int c = 0; c < 8; c++)
#pragma unroll
        for (int i = 0; i < 4; i++) osum[c][i] = 0.f;
    const __hip_bfloat16* srcs[3] = {X, Agg, Mn};
    const unsigned short* Wts[3] = {Wt1, Wt2, Wt3};
    const __hip_bfloat16* bs[3] = {b1, b2, b3};
    for (int m = 0; m < 3; m++) {
        if (m > 0) __syncthreads();  // prev iter's reads complete
        const __hip_bfloat16* S = srcs[m];
        const unsigned short* Wm = Wts[m];
        for (int idx = threadIdx.x; idx < 64 * 16; idx += 256) {
            int r = idx >> 4, ch = idx & 15;
            uint4 v = make_uint4(0u, 0u, 0u, 0u);
            int n = n0 + r;
            if (n < N) v = ((const uint4*)(S + (size_t)n * D))[ch];
            *(uint4*)&As[r * 136 + ch * 8] = v;
        }
        for (int idx = threadIdx.x; idx < 128 * 16; idx += 256) {
            int r = idx >> 4, ch = idx & 15;
            uint4 v = ((const uint4*)(Wm + (size_t)r * D))[ch];
            *(uint4*)&Bs[r * 136 + ch * 8] = v;
        }
        __syncthreads();
        const unsigned short* arow = &As[(w * 16 + n15) * 136 + quad * 8];
        bf16x8 af[4];
#pragma unroll
        for (int t = 0; t < 4; t++) af[t] = *(const bf16x8*)(arow + t * 32);
        for (int c = 0; c < 8; c++) {
            f32x4 acc = {0.f, 0.f, 0.f, 0.f};
            const unsigned short* brow = &Bs[(c * 16 + n15) * 136 + quad * 8];
#pragma unroll
            for (int t = 0; t < 4; t++)
                acc = __builtin_amdgcn_mfma_f32_16x16x32_bf16(
                    af[t], *(const bf16x8*)(brow + t * 32), acc, 0, 0, 0);
            float bb = __bfloat162float(bs[m][c * 16 + n15]);
#pragma unroll
            for (int i = 0; i < 4; i++) osum[c][i] += tanh_fast(acc[i] + bb);
        }
    }
    int f = flag[0];
    for (int c = 0; c < 8; c++) {
        int col = c * 16 + n15;
#pragma unroll
        for (int i = 0; i < 4; i++) {
            int row = n0 + w * 16 + quad * 4 + i;
            if (row < N) {
                if (f) ((float*)out)[(size_t)row * D + col] = osum[c][i];
                else   ((__hip_bfloat16*)out)[(size_t)row * D + col] =
                           __float2bfloat16(osum[c][i]);
            }
        }
    }
}

// score[e] -> eij[pos[e]] (CSR-sorted position)
__global__ __launch_bounds__(256) void edge_score_kernel(const __hip_bfloat16* __restrict__ Pkey,
                                                         const __hip_bfloat16* __restrict__ Poth,
                                                         const int* __restrict__ keys,
                                                         const int* __restrict__ oths,
                                                         const int* __restrict__ pos,
                                                         const __hip_bfloat16* __restrict__ w,
                                                         const __hip_bfloat16* __restrict__ wb,
                                                         float* __restrict__ eij, int E) {
    int wid = (int)((blockIdx.x * 256 + threadIdx.x) >> 6);
    int lane = threadIdx.x & 63;
    if (wid >= E) return;
    int key = keys[wid], oth = oths[wid];
    const __hip_bfloat162* a = (const __hip_bfloat162*)(Pkey + (size_t)key * D);
    const __hip_bfloat162* b = (const __hip_bfloat162*)(Poth + (size_t)oth * D);
    __hip_bfloat162 av = a[lane], bv = b[lane];
    __hip_bfloat162 wv = ((const __hip_bfloat162*)w)[lane];
    float p = tanh_fast(__bfloat162float(av.x) + __bfloat162float(bv.x)) * __bfloat162float(wv.x)
            + tanh_fast(__bfloat162float(av.y) + __bfloat162float(bv.y)) * __bfloat162float(wv.y);
    for (int off = 32; off; off >>= 1) p += __shfl_xor(p, off);
    if (lane == 0) eij[pos[wid]] = p + __bfloat162float(wb[0]);
}

// One wave per node: softmax over contiguous eij segment + 4x-unrolled
// X-row gather aggregation (oth_sorted is contiguous, wave-uniform).
__global__ __launch_bounds__(256) void attn_node_kernel(
    const __hip_bfloat16* __restrict__ X,
    const float* __restrict__ eij_e, const int* __restrict__ ip_e,
    const int* __restrict__ oth_e,
    const float* __restrict__ eij_r, const int* __restrict__ ip_r,
    const int* __restrict__ oth_r,
    __hip_bfloat16* __restrict__ attn_agg, int N) {
    int wid = (int)((blockIdx.x * 256 + threadIdx.x) >> 6);
    int lane = threadIdx.x & 63;
    if (wid >= N) return;
    float accx = 0.f, accy = 0.f;
    for (int side = 0; side < 2; side++) {
        const float* eij = side ? eij_r : eij_e;
        const int* ip  = side ? ip_r  : ip_e;
        const int* oth = side ? oth_r : oth_e;
        int s0 = ip[wid], s1 = ip[wid + 1];
        if (s1 == s0) continue;
        float m = 0.f;  // torch amax include_self over zeros => floor at 0
        for (int i = s0 + lane; i < s1; i += 64) m = fmaxf(m, eij[i]);
        for (int off = 32; off; off >>= 1) m = fmaxf(m, __shfl_xor(m, off));
        float ssum = 0.f;
        for (int i = s0 + lane; i < s1; i += 64) ssum += __expf(eij[i] - m);
        for (int off = 32; off; off >>= 1) ssum += __shfl_xor(ssum, off);
        float inv = 1.f / (ssum + 1e-9f);
        int i = s0;
        for (; i + 4 <= s1; i += 4) {
            int o0 = oth[i], o1 = oth[i + 1], o2 = oth[i + 2], o3 = oth[i + 3];
            float e0 = eij[i], e1 = eij[i + 1], e2 = eij[i + 2], e3 = eij[i + 3];
            __hip_bfloat162 x0 = ((const __hip_bfloat162*)(X + (size_t)o0 * D))[lane];
            __hip_bfloat162 x1 = ((const __hip_bfloat162*)(X + (size_t)o1 * D))[lane];
            __hip_bfloat162 x2 = ((const __hip_bfloat162*)(X + (size_t)o2 * D))[lane];
            __hip_bfloat162 x3 = ((const __hip_bfloat162*)(X + (size_t)o3 * D))[lane];
            float p0 = __expf(e0 - m) * inv, p1 = __expf(e1 - m) * inv;
            float p2 = __expf(e2 - m) * inv, p3 = __expf(e3 - m) * inv;
            accx += p0 * __bfloat162float(x0.x) + p1 * __bfloat162float(x1.x)
                  + p2 * __bfloat162float(x2.x) + p3 * __bfloat162float(x3.x);
            accy += p0 * __bfloat162float(x0.y) + p1 * __bfloat162float(x1.y)
                  + p2 * __bfloat162float(x2.y) + p3 * __bfloat162float(x3.y);
        }
        for (; i < s1; i++) {
            int o = oth[i];
            float p = __expf(eij[i] - m) * inv;
            __hip_bfloat162 xv = ((const __hip_bfloat162*)(X + (size_t)o * D))[lane];
            accx += p * __bfloat162float(xv.x);
            accy += p * __bfloat162float(xv.y);
        }
    }
    __hip_bfloat162 ov;
    ov.x = __float2bfloat16(accx);
    ov.y = __float2bfloat16(accy);
    ((__hip_bfloat162*)(attn_agg + (size_t)wid * D))[lane] = ov;
}

// One wave per node: mean over contiguous dst_sorted segments, unrolled 4x.
__global__ __launch_bounds__(256) void mean_node_kernel(
    const __hip_bfloat16* __restrict__ X,
    const int* __restrict__ ip_ee, const int* __restrict__ dst_ee,
    const int* __restrict__ ip_rr, const int* __restrict__ dst_rr,
    __hip_bfloat16* __restrict__ mean_agg, int N) {
    int wid = (int)((blockIdx.x * 256 + threadIdx.x) >> 6);
    int lane = threadIdx.x & 63;
    if (wid >= N) return;
    float accx = 0.f, accy = 0.f;
    int cnt = 0;
    for (int side = 0; side < 2; side++) {
        const int* ip  = side ? ip_rr  : ip_ee;
        const int* dst = side ? dst_rr : dst_ee;
        int s0 = ip[wid], s1 = ip[wid + 1];
        cnt += s1 - s0;
        int i = s0;
        for (; i + 4 <= s1; i += 4) {
            int o0 = dst[i], o1 = dst[i + 1], o2 = dst[i + 2], o3 = dst[i + 3];
            __hip_bfloat162 x0 = ((const __hip_bfloat162*)(X + (size_t)o0 * D))[lane];
            __hip_bfloat162 x1 = ((const __hip_bfloat162*)(X + (size_t)o1 * D))[lane];
            __hip_bfloat162 x2 = ((const __hip_bfloat162*)(X + (size_t)o2 * D))[lane];
            __hip_bfloat162 x3 = ((const __hip_bfloat162*)(X + (size_t)o3 * D))[lane];
            accx += __bfloat162float(x0.x) + __bfloat162float(x1.x)
                  + __bfloat162float(x2.x) + __bfloat162float(x3.x);
            accy += __bfloat162float(x0.y) + __bfloat162float(x1.y)
                  + __bfloat162float(x2.y) + __bfloat162float(x3.y);
        }
        for (; i < s1; i++) {
            __hip_bfloat162 xv = ((const __hip_bfloat162*)(X + (size_t)dst[i] * D))[lane];
            accx += __bfloat162float(xv.x);
            accy += __bfloat162float(xv.y);
        }
    }
    float inv = 1.f / fmaxf((float)cnt, 1.f);
    __hip_bfloat162 ov;
    ov.x = __float2bfloat16(accx * inv);
    ov.y = __float2bfloat16(accy * inv);
    ((__hip_bfloat162*)(mean_agg + (size_t)wid * D))[lane] = ov;
}

extern "C" void kernel_launch(void* const* d_in, const int* in_sizes, int n_in,
                              void* d_out, int out_size, void* d_ws, size_t ws_size,
                              hipStream_t stream) {
    const int* er_src = (const int*)d_in[15];
    const int* er_dst = (const int*)d_in[16];
    const int* ee_src = (const int*)d_in[17];
    const int* ee_dst = (const int*)d_in[18];
    const int* rr_src = (const int*)d_in[19];
    const int* rr_dst = (const int*)d_in[20];

    int N   = in_sizes[0] / D;
    int Eer = in_sizes[15];
    int Eee = in_sizes[17];
    int Err = in_sizes[19];

    char* ws = (char*)d_ws;
    size_t off = 0;
    auto alloc = [&](size_t bytes) -> void* {
        void* p = ws + off;
        off = (off + bytes + 255) & ~(size_t)255;
        return p;
    };
    int ntpa = (N + TILE - 1) / TILE;
    int T = 4 * ntpa;
    int* flag   = (int*)alloc(256);
    int* pos_e  = (int*)alloc((size_t)Eer * 4);
    int* pos_r  = (int*)alloc((size_t)Eer * 4);
    int* oth_e  = (int*)alloc((size_t)Eer * 4);
    int* oth_r  = (int*)alloc((size_t)Eer * 4);
    int* dst_ee = (int*)alloc((size_t)Eee * 4);
    int* dst_rr = (int*)alloc((size_t)Err * 4);
    int* indptr = (int*)alloc((size_t)4 * (N + 1) * 4);
    int* degcur = (int*)alloc((size_t)4 * N * 4);
    int* tsum   = (int*)alloc((size_t)T * 4);
    int* toff   = (int*)alloc((size_t)T * 4);
    float* eij_e = (float*)alloc((size_t)Eer * 4);
    float* eij_r = (float*)alloc((size_t)Eer * 4);
    __hip_bfloat16* Xc = (__hip_bfloat16*)alloc((size_t)N * D * 2);
    __hip_bfloat16* part0 = (__hip_bfloat16*)alloc((size_t)N * D * 2);
    __hip_bfloat16* part1 = (__hip_bfloat16*)alloc((size_t)N * D * 2);
    __hip_bfloat16* attn_agg = part0;  // parts die after 2nd edge_score
    __hip_bfloat16* mean_agg = part1;
    unsigned short* WtA = (unsigned short*)alloc((size_t)256 * 128 * 2);
    unsigned short* WtR = (unsigned short*)alloc((size_t)256 * 128 * 2);
    unsigned short* Wt1 = (unsigned short*)alloc((size_t)128 * 128 * 2);
    unsigned short* Wt2 = (unsigned short*)alloc((size_t)128 * 128 * 2);
    unsigned short* Wt3 = (unsigned short*)alloc((size_t)128 * 128 * 2);
    ConvBatch cb;
    int widx[14] = {1, 2, 3, 4, 5, 6, 7, 8, 9, 10, 11, 12, 13, 14};
    for (int i = 0; i < 14; i++) {
        cb.src[i] = d_in[widx[i]];
        cb.n[i] = in_sizes[widx[i]];
        cb.dst[i] = (__hip_bfloat16*)alloc((size_t)cb.n[i] * 2);
    }
    const __hip_bfloat16* bae = cb.dst[1];
    const __hip_bfloat16* w0w = cb.dst[2];
    const __hip_bfloat16* w0b = cb.dst[3];
    const __hip_bfloat16* bar_= cb.dst[5];
    const __hip_bfloat16* w1w = cb.dst[6];
    const __hip_bfloat16* w1b = cb.dst[7];
    const __hip_bfloat16* b1  = cb.dst[9];
    const __hip_bfloat16* b2  = cb.dst[11];
    const __hip_bfloat16* b3  = cb.dst[13];
    (void)n_in; (void)out_size;
    if (off > ws_size) return;  // diagnostic: zeros => absmax ~2.58, not NaN

    // ---- dtype detect + canonicalize ----
    detect_kernel<<<1, 256, 0, stream>>>((const unsigned short*)d_in[0], flag);
    conv_weights_kernel<<<14, 256, 0, stream>>>(cb, flag);
    conv_x_kernel<<<(N * D + 255) / 256, 256, 0, stream>>>(d_in[0], Xc, N * D, flag);
    TransBatch tb;
    tb.base[0] = d_in[1];  tb.off[0] = 0;         tb.dst[0] = WtA;
    tb.base[1] = d_in[1];  tb.off[1] = 128 * 128; tb.dst[1] = WtA + 128 * 128;
    tb.base[2] = d_in[5];  tb.off[2] = 0;         tb.dst[2] = WtR;
    tb.base[3] = d_in[5];  tb.off[3] = 128 * 128; tb.dst[3] = WtR + 128 * 128;
    tb.base[4] = d_in[9];  tb.off[4] = 0;         tb.dst[4] = Wt1;
    tb.base[5] = d_in[11]; tb.off[5] = 0;         tb.dst[5] = Wt2;
    tb.base[6] = d_in[13]; tb.off[6] = 0;         tb.dst[6] = Wt3;
    trans_kernel<<<7, 256, 0, stream>>>(tb, flag);

    // ---- CSR build (4 keys: er_src, er_dst, ee_src, rr_src) ----
    zero_kernel<<<(4 * N + 255) / 256, 256, 0, stream>>>(degcur, 4 * N);
    count_kernel<<<(Eer + 255) / 256, 256, 0, stream>>>(er_src, Eer, degcur);
    count_kernel<<<(Eer + 255) / 256, 256, 0, stream>>>(er_dst, Eer, degcur + N);
    count_kernel<<<(Eee + 255) / 256, 256, 0, stream>>>(ee_src, Eee, degcur + 2 * N);
    count_kernel<<<(Err + 255) / 256, 256, 0, stream>>>(rr_src, Err, degcur + 3 * N);
    scan_partial_kernel<<<T, 256, 0, stream>>>(degcur, tsum, N, ntpa);
    scan_tiles_kernel<<<1, 256, 0, stream>>>(tsum, toff, indptr, N, ntpa);
    scan_final_kernel<<<T, 256, 0, stream>>>(degcur, toff, indptr, N, ntpa);
    scatter_attn_kernel<<<(Eer + 255) / 256, 256, 0, stream>>>(er_src, er_dst, Eer,
                                                               degcur, pos_e, oth_e);
    scatter_attn_kernel<<<(Eer + 255) / 256, 256, 0, stream>>>(er_dst, er_src, Eer,
                                                               degcur + N, pos_r, oth_r);
    scatter_mean_kernel<<<(Eee + 255) / 256, 256, 0, stream>>>(ee_src, ee_dst, Eee,
                                                               degcur + 2 * N, dst_ee);
    scatter_mean_kernel<<<(Err + 255) / 256, 256, 0, stream>>>(rr_src, rr_dst, Err,
                                                               degcur + 3 * N, dst_rr);

    int GB = (N + 63) / 64;
    int EW = (Eer + 3) / 4;  // one wave per edge

    // entity side: pair=[r,h]@Wae; key=src(h part,+bae), oth=dst(r part)
    gemm2_mfma_kernel<<<GB, 256, 0, stream>>>(Xc, WtA, bae, part0, part1, N);
    edge_score_kernel<<<EW, 256, 0, stream>>>(part1, part0, er_src, er_dst, pos_e,
                                              w0w, w0b, eij_e, Eer);

    // relation side: pair=[h,r]@War; key=dst(r part,+bar), oth=src(h part)
    gemm2_mfma_kernel<<<GB, 256, 0, stream>>>(Xc, WtR, bar_, part0, part1, N);
    edge_score_kernel<<<EW, 256, 0, stream>>>(part1, part0, er_dst, er_src, pos_r,
                                              w1w, w1b, eij_r, Eer);

    int NW = (N + 3) / 4;  // one wave per node
    attn_node_kernel<<<NW, 256, 0, stream>>>(Xc, eij_e, indptr, oth_e,
                                             eij_r, indptr + (N + 1), oth_r,
                                             attn_agg, N);
    mean_node_kernel<<<NW, 256, 0, stream>>>(Xc, indptr + 2 * (N + 1), dst_ee,
                                             indptr + 3 * (N + 1), dst_rr,
                                             mean_agg, N);
    final_mfma_kernel<<<GB, 256, 0, stream>>>(Xc, attn_agg, mean_agg,
                                              Wt1, b1, Wt2, b2, Wt3, b3,
                                              d_out, flag, N);
}